// Round 7
// baseline (2389.812 us; speedup 1.0000x reference)
//
#include <hip/hip_runtime.h>
#include <hip/hip_bf16.h>
#include <math.h>

#define NN 50000
#define NNP 50048          // padded to multiple of 128
#define NE 800000
#define NG 512
#define DIN 128
#define HD 256
#define DOUT 128
#define NL 5
#define H4 1024

typedef _Float16 f16x8 __attribute__((ext_vector_type(8)));
typedef _Float16 f16x4 __attribute__((ext_vector_type(4)));
typedef float f32x4 __attribute__((ext_vector_type(4)));

__device__ __forceinline__ float gelu_exact(float x) {
    return 0.5f * x * (1.0f + erff(x * 0.70710678118654752f));
}

__device__ __forceinline__ void gl_lds16(const _Float16* g, _Float16* l) {
    __builtin_amdgcn_global_load_lds(
        (const __attribute__((address_space(1))) unsigned int*)g,
        (__attribute__((address_space(3))) unsigned int*)l, 16, 0, 0);
}

// ---------------- graph meta ----------------
__global__ void k_hist(const int* __restrict__ idx, int* __restrict__ cnt, int n) {
    int i = blockIdx.x * blockDim.x + threadIdx.x;
    if (i < n) atomicAdd(&cnt[idx[i]], 1);
}

__global__ void k_scan_part(const int* __restrict__ in, int* __restrict__ bsum, int n) {
    __shared__ int buf[256];
    int i = blockIdx.x * 256 + threadIdx.x;
    buf[threadIdx.x] = (i < n) ? in[i] : 0;
    __syncthreads();
    for (int off = 128; off > 0; off >>= 1) {
        if (threadIdx.x < off) buf[threadIdx.x] += buf[threadIdx.x + off];
        __syncthreads();
    }
    if (threadIdx.x == 0) bsum[blockIdx.x] = buf[0];
}

__global__ void k_scan_mid(const int* __restrict__ bsum, int* __restrict__ bexcl, int nb,
                           int* __restrict__ out, int n) {
    __shared__ int buf[1024];
    int t = threadIdx.x;
    int v = (t < nb) ? bsum[t] : 0;
    buf[t] = v;
    __syncthreads();
    for (int off = 1; off < 1024; off <<= 1) {
        int x = (t >= off) ? buf[t - off] : 0;
        __syncthreads();
        buf[t] += x;
        __syncthreads();
    }
    if (t < nb) bexcl[t] = buf[t] - v;
    if (t == 1023) out[n] = buf[1023];
}

__global__ void k_scan_out(const int* __restrict__ in, const int* __restrict__ bexcl,
                           int* __restrict__ out, int n) {
    __shared__ int buf[256];
    int i = blockIdx.x * 256 + threadIdx.x;
    int t = threadIdx.x;
    int v = (i < n) ? in[i] : 0;
    buf[t] = v;
    __syncthreads();
    for (int off = 1; off < 256; off <<= 1) {
        int x = (t >= off) ? buf[t - off] : 0;
        __syncthreads();
        buf[t] += x;
        __syncthreads();
    }
    if (i < n) out[i] = bexcl[blockIdx.x] + buf[t] - v;
}

__global__ void k_fill_csr(const int* __restrict__ src, const int* __restrict__ dst,
                           const int* __restrict__ eoff, int* __restrict__ cursor,
                           int* __restrict__ csr, int n) {
    int e = blockIdx.x * blockDim.x + threadIdx.x;
    if (e < n) {
        int d = dst[e];
        int p = atomicAdd(&cursor[d], 1);
        csr[eoff[d] + p] = src[e];
    }
}

// ---------------- converts ----------------
__global__ void k_cvt16(const float* __restrict__ in, _Float16* __restrict__ out, int n4) {
    int i = blockIdx.x * blockDim.x + threadIdx.x;
    if (i < n4) {
        float4 v = *(const float4*)&in[i * 4];
        f16x4 o = { (_Float16)v.x, (_Float16)v.y, (_Float16)v.z, (_Float16)v.w };
        *(f16x4*)&out[i * 4] = o;
    }
}

// transpose + convert: Wt[l][n][k] = (fp16) W[l][k][n]
__global__ void k_wt(const float* __restrict__ W, _Float16* __restrict__ Wt, int K, int N) {
    __shared__ float tile[32][33];
    size_t mat = (size_t)K * N;
    W += blockIdx.z * mat;
    Wt += blockIdx.z * mat;
    int n0 = blockIdx.x * 32, k0 = blockIdx.y * 32;
    for (int i = threadIdx.y; i < 32; i += 8)
        tile[i][threadIdx.x] = W[(size_t)(k0 + i) * N + n0 + threadIdx.x];
    __syncthreads();
    for (int i = threadIdx.y; i < 32; i += 8)
        Wt[(size_t)(n0 + i) * K + k0 + threadIdx.x] = (_Float16)tile[threadIdx.x][i];
}

// ---------------- aggregation ----------------
// one wave per node; WAVE-UNIFORM loop bounds; 8 edges/iter
__global__ __launch_bounds__(256) void k_agg16(const _Float16* __restrict__ h16,
                                               const int* __restrict__ eoff,
                                               const int* __restrict__ csr,
                                               _Float16* __restrict__ out) {
    int node = blockIdx.x * 4 + (threadIdx.x >> 6);
    int lane = threadIdx.x & 63;
    int half = lane >> 5, l = lane & 31;
    f16x8 mine = *(const f16x8*)&h16[(size_t)node * HD + l * 8];
    float acc[8];
#pragma unroll
    for (int q = 0; q < 8; ++q) acc[q] = half ? 0.f : (float)mine[q];
    int s = eoff[node], e = eoff[node + 1];
    for (int base = s; base < e; base += 64) {
        int myi = base + lane;
        int vidx = (myi < e) ? csr[myi] : 0;
        int cnt = min(64, e - base);
        int jj = 0;
        for (; jj + 7 < cnt; jj += 8) {
            int s0 = __shfl(vidx, jj + half);
            int s1 = __shfl(vidx, jj + 2 + half);
            int s2 = __shfl(vidx, jj + 4 + half);
            int s3 = __shfl(vidx, jj + 6 + half);
            f16x8 v0 = *(const f16x8*)&h16[(size_t)s0 * HD + l * 8];
            f16x8 v1 = *(const f16x8*)&h16[(size_t)s1 * HD + l * 8];
            f16x8 v2 = *(const f16x8*)&h16[(size_t)s2 * HD + l * 8];
            f16x8 v3 = *(const f16x8*)&h16[(size_t)s3 * HD + l * 8];
#pragma unroll
            for (int q = 0; q < 8; ++q)
                acc[q] += ((float)v0[q] + (float)v1[q]) + ((float)v2[q] + (float)v3[q]);
        }
        for (; jj + 3 < cnt; jj += 4) {
            int s0 = __shfl(vidx, jj + half);
            int s1 = __shfl(vidx, jj + 2 + half);
            f16x8 v0 = *(const f16x8*)&h16[(size_t)s0 * HD + l * 8];
            f16x8 v1 = *(const f16x8*)&h16[(size_t)s1 * HD + l * 8];
#pragma unroll
            for (int q = 0; q < 8; ++q) acc[q] += (float)v0[q] + (float)v1[q];
        }
        for (; jj < cnt; jj += 2) {
            int i0 = jj + half;
            int s0 = __shfl(vidx, i0);
            if (i0 < cnt) {
                f16x8 v0 = *(const f16x8*)&h16[(size_t)s0 * HD + l * 8];
#pragma unroll
                for (int q = 0; q < 8; ++q) acc[q] += (float)v0[q];
            }
        }
    }
#pragma unroll
    for (int q = 0; q < 8; ++q) acc[q] += __shfl_xor(acc[q], 32);
    if (!half) {
        f16x8 o;
#pragma unroll
        for (int q = 0; q < 8; ++q) o[q] = (_Float16)acc[q];
        *(f16x8*)&out[(size_t)node * HD + l * 8] = o;
    }
}

// ---------------- fused virtual-node chain: one block per group ----------------
// outvn[g] = ffnn(vn + ffnn(mean_pool(h16)[g], uW*, ub*), pW*, pb*)   (all fp32 math)
__global__ __launch_bounds__(256) void k_vn(const _Float16* __restrict__ h16,
                                            const int* __restrict__ goff,
                                            const float* __restrict__ uW1, const float* __restrict__ ub1,
                                            const float* __restrict__ uW2, const float* __restrict__ ub2,
                                            const float* __restrict__ pW1, const float* __restrict__ pb1,
                                            const float* __restrict__ pW2, const float* __restrict__ pb2,
                                            const float* __restrict__ vn,
                                            float* __restrict__ outvn) {
    __shared__ float pool[HD], u[HD], v[H4], pr[HD];
    int g = blockIdx.x, t = threadIdx.x;
    int s = goff[g], e = goff[g + 1];
    float acc = 0.f;
    for (int r = s; r < e; ++r) acc += (float)h16[(size_t)r * HD + t];
    pool[t] = acc / (float)max(e - s, 1);
    __syncthreads();
    float a = ub1[t];
#pragma unroll 4
    for (int k = 0; k < HD; ++k) a += pool[k] * uW1[(size_t)k * HD + t];
    u[t] = gelu_exact(a);
    __syncthreads();
    {
        float4 av = *(const float4*)&ub2[4 * t];
        float4 vv = *(const float4*)&vn[4 * t];
        av.x += vv.x; av.y += vv.y; av.z += vv.z; av.w += vv.w;
#pragma unroll 2
        for (int k = 0; k < HD; ++k) {
            float uk = u[k];
            float4 wv = *(const float4*)&uW2[(size_t)k * H4 + 4 * t];
            av.x += uk * wv.x; av.y += uk * wv.y; av.z += uk * wv.z; av.w += uk * wv.w;
        }
        *(float4*)&v[4 * t] = av;
    }
    __syncthreads();
    float b = pb1[t];
#pragma unroll 4
    for (int k = 0; k < H4; ++k) b += v[k] * pW1[(size_t)k * HD + t];
    pr[t] = gelu_exact(b);
    __syncthreads();
    float c = pb2[t];
#pragma unroll 4
    for (int k = 0; k < HD; ++k) c += pr[k] * pW2[(size_t)k * HD + t];
    outvn[(size_t)g * HD + t] = c;
}

// ---------------- fused post head: one block per group ----------------
__global__ __launch_bounds__(256) void k_post(const _Float16* __restrict__ h16,
                                              const int* __restrict__ goff,
                                              const float* __restrict__ W1, const float* __restrict__ b1,
                                              const float* __restrict__ W2, const float* __restrict__ b2,
                                              float* __restrict__ out) {
    __shared__ float pool[HD], u[HD];
    int g = blockIdx.x, t = threadIdx.x;
    int s = goff[g], e = goff[g + 1];
    float acc = 0.f;
    for (int r = s; r < e; ++r) acc += (float)h16[(size_t)r * HD + t];
    pool[t] = acc / (float)max(e - s, 1);
    __syncthreads();
    float a = b1[t];
#pragma unroll 4
    for (int k = 0; k < HD; ++k) a += pool[k] * W1[(size_t)k * HD + t];
    u[t] = gelu_exact(a);
    __syncthreads();
    if (t < DOUT) {
        float c = b2[t];
#pragma unroll 4
        for (int k = 0; k < HD; ++k) c += u[k] * W2[(size_t)k * DOUT + t];
        out[(size_t)g * DOUT + t] = c;
    }
}

// ---------------- batch norm finalize (also re-zeroes stat for next layer) ----
__global__ void k_bn_final(float* __restrict__ stat,
                           const float* __restrict__ gamma, const float* __restrict__ beta,
                           float* __restrict__ scale, float* __restrict__ shift) {
    int c = threadIdx.x;
    float mu = stat[c] * (1.0f / NN);
    float var = stat[HD + c] * (1.0f / NN) - mu * mu;
    float rs = rsqrtf(var + 1e-5f);
    float sc = rs * gamma[c];
    scale[c] = sc;
    shift[c] = beta[c] - mu * sc;
    stat[c] = 0.f;
    stat[HD + c] = 0.f;
}

__device__ __forceinline__ void bnpack(float4 g0, float4 g1, float4 s0, float4 s1,
                                       float4 h0, float4 h1, float4 o0, float4 o1, f16x8& r) {
    r[0] = (_Float16)(g0.x * s0.x + h0.x + o0.x);
    r[1] = (_Float16)(g0.y * s0.y + h0.y + o0.y);
    r[2] = (_Float16)(g0.z * s0.z + h0.z + o0.z);
    r[3] = (_Float16)(g0.w * s0.w + h0.w + o0.w);
    r[4] = (_Float16)(g1.x * s1.x + h1.x + o1.x);
    r[5] = (_Float16)(g1.y * s1.y + h1.y + o1.y);
    r[6] = (_Float16)(g1.z * s1.z + h1.z + o1.z);
    r[7] = (_Float16)(g1.w * s1.w + h1.w + o1.w);
}

// ---------------- MFMA fp16 GEMM (128x128 tile, double-buffered) ----------------
// RES: +R (fp32). RESBN: +R*bnsc+bnsh. STATS: fused BN column stats.
// ABN: A-operand is fp32 A32 transformed on-stage: a = A32*bnsc+bnsh + ovn[batch[row]]
template <bool GELU, bool RES, bool RESBN, bool STATS, bool ABN, bool O32, bool O16>
__global__ __launch_bounds__(256) void k_mgemm(const _Float16* __restrict__ A,
                                               const float* __restrict__ A32,
                                               const _Float16* __restrict__ Wt,
                                               const float* __restrict__ bias,
                                               const float* __restrict__ R,
                                               const float* __restrict__ bnsc,
                                               const float* __restrict__ bnsh,
                                               const float* __restrict__ ovn,
                                               const int* __restrict__ batchv,
                                               float* __restrict__ stat,
                                               float* __restrict__ C32,
                                               _Float16* __restrict__ C16,
                                               int M, int N, int K) {
    __shared__ _Float16 As[2][4][128][8];
    __shared__ _Float16 Bs[2][4][128][8];
    const int t = threadIdx.x;
    const int w = t >> 6, lane = t & 63;
    const int wr = w & 1, wc = w >> 1;
    const int m0 = blockIdx.y * 128, n0 = blockIdx.x * 128;
    const int kb = lane >> 4, fr = lane & 15;

    f32x4 acc[4][4];
#pragma unroll
    for (int mi = 0; mi < 4; ++mi)
#pragma unroll
        for (int ni = 0; ni < 4; ++ni) acc[mi][ni] = (f32x4){0.f, 0.f, 0.f, 0.f};

    const _Float16* gA0 = nullptr;
    const _Float16* gA1 = nullptr;
    int b0 = 0, b1r = 0;
    if constexpr (!ABN) {
        gA0 = A + (size_t)(m0 + lane) * K + w * 8;
        gA1 = A + (size_t)(m0 + 64 + lane) * K + w * 8;
    } else {
        b0 = batchv[min(m0 + lane, M - 1)];
        b1r = batchv[min(m0 + 64 + lane, M - 1)];
    }
    const _Float16* gB0 = Wt + (size_t)(n0 + lane) * K + w * 8;
    const _Float16* gB1 = Wt + (size_t)(n0 + 64 + lane) * K + w * 8;

    auto stage = [&](int buf, int k0) {
        if constexpr (ABN) {
            const int c0 = k0 + w * 8;
            float4 s0 = *(const float4*)&bnsc[c0];
            float4 s1 = *(const float4*)&bnsc[c0 + 4];
            float4 h0 = *(const float4*)&bnsh[c0];
            float4 h1 = *(const float4*)&bnsh[c0 + 4];
            const float* ga = A32 + (size_t)(m0 + lane) * K + c0;
            const float* gb = A32 + (size_t)(m0 + 64 + lane) * K + c0;
            float4 ga0 = *(const float4*)ga;
            float4 ga1 = *(const float4*)(ga + 4);
            float4 gb0 = *(const float4*)gb;
            float4 gb1 = *(const float4*)(gb + 4);
            float4 oa0 = *(const float4*)&ovn[(size_t)b0 * K + c0];
            float4 oa1 = *(const float4*)&ovn[(size_t)b0 * K + c0 + 4];
            float4 ob0 = *(const float4*)&ovn[(size_t)b1r * K + c0];
            float4 ob1 = *(const float4*)&ovn[(size_t)b1r * K + c0 + 4];
            f16x8 r0, r1;
            bnpack(ga0, ga1, s0, s1, h0, h1, oa0, oa1, r0);
            bnpack(gb0, gb1, s0, s1, h0, h1, ob0, ob1, r1);
            *(f16x8*)&As[buf][w][lane][0] = r0;
            *(f16x8*)&As[buf][w][64 + lane][0] = r1;
        } else {
            gl_lds16(gA0 + k0, &As[buf][w][0][0]);
            gl_lds16(gA1 + k0, &As[buf][w][64][0]);
        }
        gl_lds16(gB0 + k0, &Bs[buf][w][0][0]);
        gl_lds16(gB1 + k0, &Bs[buf][w][64][0]);
    };

    const int nt = K >> 5;
    stage(0, 0);
    __syncthreads();
    for (int tt = 0; tt < nt; ++tt) {
        const int cur = tt & 1;
        if (tt + 1 < nt) stage(cur ^ 1, (tt + 1) << 5);
        f16x8 af[4], bf[4];
#pragma unroll
        for (int mi = 0; mi < 4; ++mi)
            af[mi] = *(const f16x8*)&As[cur][kb][wr * 64 + mi * 16 + fr][0];
#pragma unroll
        for (int ni = 0; ni < 4; ++ni)
            bf[ni] = *(const f16x8*)&Bs[cur][kb][wc * 64 + ni * 16 + fr][0];
#pragma unroll
        for (int mi = 0; mi < 4; ++mi)
#pragma unroll
            for (int ni = 0; ni < 4; ++ni)
                acc[mi][ni] = __builtin_amdgcn_mfma_f32_16x16x32_f16(af[mi], bf[ni], acc[mi][ni], 0, 0, 0);
        __syncthreads();
    }

    const int rr = lane >> 4;
    float cs[4] = {0.f, 0.f, 0.f, 0.f}, cq[4] = {0.f, 0.f, 0.f, 0.f};
#pragma unroll
    for (int mi = 0; mi < 4; ++mi) {
#pragma unroll
        for (int reg = 0; reg < 4; ++reg) {
            int m = m0 + wr * 64 + mi * 16 + rr * 4 + reg;
            if (m < M) {
#pragma unroll
                for (int ni = 0; ni < 4; ++ni) {
                    int n = n0 + wc * 64 + ni * 16 + fr;
                    float v = acc[mi][ni][reg] + bias[n];
                    if (GELU) v = gelu_exact(v);
                    if (RES) v += R[(size_t)m * N + n];
                    if (RESBN) v += R[(size_t)m * N + n] * bnsc[n] + bnsh[n];
                    if (O32) C32[(size_t)m * N + n] = v;
                    if (O16) C16[(size_t)m * N + n] = (_Float16)v;
                    if (STATS) { cs[ni] += v; cq[ni] += v * v; }
                }
            }
        }
    }
    if constexpr (STATS) {
        __shared__ float sred[2][128], qred[2][128];
#pragma unroll
        for (int ni = 0; ni < 4; ++ni) {
            cs[ni] += __shfl_xor(cs[ni], 16); cs[ni] += __shfl_xor(cs[ni], 32);
            cq[ni] += __shfl_xor(cq[ni], 16); cq[ni] += __shfl_xor(cq[ni], 32);
        }
        if (rr == 0) {
#pragma unroll
            for (int ni = 0; ni < 4; ++ni) {
                sred[wr][wc * 64 + ni * 16 + fr] = cs[ni];
                qred[wr][wc * 64 + ni * 16 + fr] = cq[ni];
            }
        }
        __syncthreads();
        if (t < 128) {
            atomicAdd(&stat[n0 + t], sred[0][t] + sred[1][t]);
            atomicAdd(&stat[HD + n0 + t], qred[0][t] + qred[1][t]);
        }
    }
}

// helpers
static inline void mg_gelu(hipStream_t st, const _Float16* A, const _Float16* Wt,
                           const float* bias, _Float16* C16, int M, int N, int K) {
    dim3 g(N / 128, (M + 127) / 128), b(256);
    k_mgemm<true, false, false, false, false, false, true><<<g, b, 0, st>>>(
        A, nullptr, Wt, bias, nullptr, nullptr, nullptr, nullptr, nullptr, nullptr, nullptr, C16, M, N, K);
}
static inline void mg_both(hipStream_t st, const _Float16* A, const _Float16* Wt,
                           const float* bias, float* C32, _Float16* C16, int M, int N, int K) {
    dim3 g(N / 128, (M + 127) / 128), b(256);
    k_mgemm<false, false, false, false, false, true, true><<<g, b, 0, st>>>(
        A, nullptr, Wt, bias, nullptr, nullptr, nullptr, nullptr, nullptr, nullptr, C32, C16, M, N, K);
}
static inline void mg_res32_stats(hipStream_t st, const _Float16* A, const _Float16* Wt,
                                  const float* bias, const float* R, float* stat,
                                  float* C32, int M, int N, int K) {
    dim3 g(N / 128, (M + 127) / 128), b(256);
    k_mgemm<false, true, false, true, false, true, false><<<g, b, 0, st>>>(
        A, nullptr, Wt, bias, R, nullptr, nullptr, nullptr, nullptr, stat, C32, nullptr, M, N, K);
}
static inline void mg_gelu_abn(hipStream_t st, const float* A32, const _Float16* Wt,
                               const float* bias, const float* bnsc, const float* bnsh,
                               const float* ovn, const int* batchv, _Float16* C16,
                               int M, int N, int K) {
    dim3 g(N / 128, (M + 127) / 128), b(256);
    k_mgemm<true, false, false, false, true, false, true><<<g, b, 0, st>>>(
        nullptr, A32, Wt, bias, nullptr, bnsc, bnsh, ovn, batchv, nullptr, nullptr, C16, M, N, K);
}
static inline void mg_resbn_both(hipStream_t st, const _Float16* A, const _Float16* Wt,
                                 const float* bias, const float* R, const float* bnsc,
                                 const float* bnsh, float* C32, _Float16* C16,
                                 int M, int N, int K) {
    dim3 g(N / 128, (M + 127) / 128), b(256);
    k_mgemm<false, false, true, false, false, true, true><<<g, b, 0, st>>>(
        A, nullptr, Wt, bias, R, bnsc, bnsh, nullptr, nullptr, nullptr, C32, C16, M, N, K);
}

extern "C" void kernel_launch(void* const* d_in, const int* in_sizes, int n_in,
                              void* d_out, int out_size, void* d_ws, size_t ws_size,
                              hipStream_t stream) {
    const float* x       = (const float*)d_in[0];
    const int*   ei      = (const int*)d_in[1];
    const int*   batch   = (const int*)d_in[2];
    const float* pre_W1  = (const float*)d_in[3];
    const float* pre_b1  = (const float*)d_in[4];
    const float* pre_W2  = (const float*)d_in[5];
    const float* pre_b2  = (const float*)d_in[6];
    const float* gin_W1  = (const float*)d_in[7];
    const float* gin_b1  = (const float*)d_in[8];
    const float* gin_W2  = (const float*)d_in[9];
    const float* gin_b2  = (const float*)d_in[10];
    const float* ffn_W1  = (const float*)d_in[11];
    const float* ffn_b1  = (const float*)d_in[12];
    const float* ffn_W2  = (const float*)d_in[13];
    const float* ffn_b2  = (const float*)d_in[14];
    const float* upd_W1  = (const float*)d_in[15];
    const float* upd_b1  = (const float*)d_in[16];
    const float* upd_W2  = (const float*)d_in[17];
    const float* upd_b2  = (const float*)d_in[18];
    const float* prop_W1 = (const float*)d_in[19];
    const float* prop_b1 = (const float*)d_in[20];
    const float* prop_W2 = (const float*)d_in[21];
    const float* prop_b2 = (const float*)d_in[22];
    const float* bn_gamma= (const float*)d_in[23];
    const float* bn_beta = (const float*)d_in[24];
    const float* vn      = (const float*)d_in[25];
    const float* post_W1 = (const float*)d_in[26];
    const float* post_b1 = (const float*)d_in[27];
    const float* post_W2 = (const float*)d_in[28];
    const float* post_b2 = (const float*)d_in[29];
    float* out = (float*)d_out;

    const int* e_src = ei;
    const int* e_dst = ei + NE;

    // ---------- workspace layout ----------
    char* p = (char*)d_ws;
    auto alloc = [&](size_t bytes) -> char* {
        char* r = p;
        p += (bytes + 255) & ~(size_t)255;
        return r;
    };
    float*    h32    = (float*)alloc((size_t)NNP * HD * 4);   // fp32 backbone
    float*    g32    = (float*)alloc((size_t)NNP * HD * 4);   // gin2 out (raw)
    _Float16* h16    = (_Float16*)alloc((size_t)NNP * HD * 2);
    _Float16* t16a   = (_Float16*)alloc((size_t)NNP * HD * 2);
    _Float16* t16b   = (_Float16*)alloc((size_t)NNP * HD * 2);  // aliases x16 pre-launch
    float*    outvn32= (float*)alloc((size_t)NG * HD * 4);
    float*    bnstat = (float*)alloc(2 * HD * 4);
    float*    bnscale= (float*)alloc(HD * 4);
    float*    bnshift= (float*)alloc(HD * 4);
    _Float16* preW1t = (_Float16*)alloc((size_t)HD * DIN * 2);
    _Float16* preW2t = (_Float16*)alloc((size_t)HD * HD * 2);
    _Float16* ginW1t = (_Float16*)alloc((size_t)NL * HD * HD * 2);
    _Float16* ginW2t = (_Float16*)alloc((size_t)NL * HD * HD * 2);
    _Float16* ffnW1t = (_Float16*)alloc((size_t)NL * HD * HD * 2);
    _Float16* ffnW2t = (_Float16*)alloc((size_t)NL * HD * HD * 2);
    int* gcount = (int*)alloc(NG * 4);
    int* goff   = (int*)alloc((NG + 1) * 4);
    int* deg    = (int*)alloc(NN * 4);
    int* eoff   = (int*)alloc((NN + 1) * 4);
    int* cursor = (int*)alloc(NN * 4);
    int* csr    = (int*)alloc((size_t)NE * 4);
    int* bsum   = (int*)alloc(1024 * 4);
    int* bexcl  = (int*)alloc(1024 * 4);
    _Float16* x16 = t16b;  // alias: only live before pre-GEMM1

    // ---------- zero counters (gcount..cursor contiguous span) + bnstat ----------
    {
        size_t span = (size_t)((char*)(cursor + NN) - (char*)gcount);
        hipMemsetAsync(gcount, 0, span, stream);
        hipMemsetAsync(bnstat, 0, 2 * HD * 4, stream);
    }
    hipLaunchKernelGGL(k_hist, dim3((NN + 255) / 256), dim3(256), 0, stream, batch, gcount, NN);
    hipLaunchKernelGGL(k_hist, dim3((NE + 255) / 256), dim3(256), 0, stream, e_dst, deg, NE);
    {
        int nbG = (NG + 255) / 256;
        hipLaunchKernelGGL(k_scan_part, dim3(nbG), dim3(256), 0, stream, gcount, bsum, NG);
        hipLaunchKernelGGL(k_scan_mid, dim3(1), dim3(1024), 0, stream, bsum, bexcl, nbG, goff, NG);
        hipLaunchKernelGGL(k_scan_out, dim3(nbG), dim3(256), 0, stream, gcount, bexcl, goff, NG);
        int nbN = (NN + 255) / 256;
        hipLaunchKernelGGL(k_scan_part, dim3(nbN), dim3(256), 0, stream, deg, bsum, NN);
        hipLaunchKernelGGL(k_scan_mid, dim3(1), dim3(1024), 0, stream, bsum, bexcl, nbN, eoff, NN);
        hipLaunchKernelGGL(k_scan_out, dim3(nbN), dim3(256), 0, stream, deg, bexcl, eoff, NN);
    }
    hipLaunchKernelGGL(k_fill_csr, dim3((NE + 255) / 256), dim3(256), 0, stream, e_src, e_dst, eoff, cursor, csr, NE);

    // ---------- weight convert + transpose (only MFMA-consumed weights) ----------
    dim3 tb(32, 8);
    hipLaunchKernelGGL(k_wt, dim3(HD / 32, DIN / 32, 1), tb, 0, stream, pre_W1, preW1t, DIN, HD);
    hipLaunchKernelGGL(k_wt, dim3(HD / 32, HD / 32, 1), tb, 0, stream, pre_W2, preW2t, HD, HD);
    hipLaunchKernelGGL(k_wt, dim3(HD / 32, HD / 32, NL), tb, 0, stream, gin_W1, ginW1t, HD, HD);
    hipLaunchKernelGGL(k_wt, dim3(HD / 32, HD / 32, NL), tb, 0, stream, gin_W2, ginW2t, HD, HD);
    hipLaunchKernelGGL(k_wt, dim3(HD / 32, HD / 32, NL), tb, 0, stream, ffn_W1, ffnW1t, HD, HD);
    hipLaunchKernelGGL(k_wt, dim3(HD / 32, HD / 32, NL), tb, 0, stream, ffn_W2, ffnW2t, HD, HD);

    // x -> fp16
    int n4 = NN * DIN / 4;
    hipLaunchKernelGGL(k_cvt16, dim3((n4 + 255) / 256), dim3(256), 0, stream, x, x16, n4);

    // ---------- pre-FFNN ----------
    mg_gelu(stream, x16, preW1t, pre_b1, t16a, NN, HD, DIN);
    mg_both(stream, t16a, preW2t, pre_b2, h32, h16, NN, HD, HD);

    for (int i = 0; i < NL; ++i) {
        const _Float16* gW1 = ginW1t + (size_t)i * HD * HD;
        const _Float16* gW2 = ginW2t + (size_t)i * HD * HD;
        const _Float16* fW1 = ffnW1t + (size_t)i * HD * HD;
        const _Float16* fW2 = ffnW2t + (size_t)i * HD * HD;

        // fused virtual-node chain (fp32 math, original weight layouts)
        hipLaunchKernelGGL(k_vn, dim3(NG), dim3(256), 0, stream, h16, goff,
                           upd_W1 + (size_t)i * HD * HD, upd_b1 + (size_t)i * HD,
                           upd_W2 + (size_t)i * HD * H4, upd_b2 + (size_t)i * H4,
                           prop_W1 + (size_t)i * H4 * HD, prop_b1 + (size_t)i * HD,
                           prop_W2 + (size_t)i * HD * HD, prop_b2 + (size_t)i * HD,
                           vn, outvn32);

        // GIN: t16a = agg(h16); t16b = gelu(t16a@W1+b); g32 = t16b@W2+b + h32 (+fused BN stats)
        hipLaunchKernelGGL(k_agg16, dim3(NN / 4), dim3(256), 0, stream, h16, eoff, csr, t16a);
        mg_gelu(stream, t16a, gW1, gin_b1 + (size_t)i * HD, t16b, NN, HD, HD);
        mg_res32_stats(stream, t16b, gW2, gin_b2 + (size_t)i * HD, h32, bnstat, g32, NN, HD, HD);

        // BN finalize (re-zeroes stat)
        hipLaunchKernelGGL(k_bn_final, dim3(1), dim3(HD), 0, stream, bnstat,
                           bn_gamma + (size_t)i * HD, bn_beta + (size_t)i * HD, bnscale, bnshift);

        // FFN1 with fused BN+VN A-transform: t16b = gelu((bn(g32)+ovn)@fW1+b)
        mg_gelu_abn(stream, g32, fW1, ffn_b1 + (size_t)i * HD, bnscale, bnshift,
                    outvn32, batch, t16b, NN, HD, HD);
        // FFN2: h32/h16 = t16b@fW2+b + (g32*scale+shift)
        mg_resbn_both(stream, t16b, fW2, ffn_b2 + (size_t)i * HD, g32, bnscale, bnshift,
                      h32, h16, NN, HD, HD);
    }

    // ---------- post (fused pool + 2 matvecs) ----------
    hipLaunchKernelGGL(k_post, dim3(NG), dim3(256), 0, stream, h16, goff,
                       post_W1, post_b1, post_W2, post_b2, out);
}

// Round 8
// 2211.675 us; speedup vs baseline: 1.0805x; 1.0805x over previous
//
#include <hip/hip_runtime.h>
#include <hip/hip_bf16.h>
#include <math.h>

#define NN 50000
#define NNP 50048          // padded to multiple of 128
#define NE 800000
#define NG 512
#define DIN 128
#define HD 256
#define DOUT 128
#define NL 5
#define H4 1024

typedef _Float16 f16x8 __attribute__((ext_vector_type(8)));
typedef _Float16 f16x4 __attribute__((ext_vector_type(4)));
typedef float f32x4 __attribute__((ext_vector_type(4)));

__device__ __forceinline__ float gelu_exact(float x) {
    return 0.5f * x * (1.0f + erff(x * 0.70710678118654752f));
}

__device__ __forceinline__ void gl_lds16(const _Float16* g, _Float16* l) {
    __builtin_amdgcn_global_load_lds(
        (const __attribute__((address_space(1))) unsigned int*)g,
        (__attribute__((address_space(3))) unsigned int*)l, 16, 0, 0);
}

// ---------------- graph meta ----------------
__global__ void k_hist(const int* __restrict__ idx, int* __restrict__ cnt, int n) {
    int i = blockIdx.x * blockDim.x + threadIdx.x;
    if (i < n) atomicAdd(&cnt[idx[i]], 1);
}

__global__ void k_scan_part(const int* __restrict__ in, int* __restrict__ bsum, int n) {
    __shared__ int buf[256];
    int i = blockIdx.x * 256 + threadIdx.x;
    buf[threadIdx.x] = (i < n) ? in[i] : 0;
    __syncthreads();
    for (int off = 128; off > 0; off >>= 1) {
        if (threadIdx.x < off) buf[threadIdx.x] += buf[threadIdx.x + off];
        __syncthreads();
    }
    if (threadIdx.x == 0) bsum[blockIdx.x] = buf[0];
}

__global__ void k_scan_mid(const int* __restrict__ bsum, int* __restrict__ bexcl, int nb,
                           int* __restrict__ out, int n) {
    __shared__ int buf[1024];
    int t = threadIdx.x;
    int v = (t < nb) ? bsum[t] : 0;
    buf[t] = v;
    __syncthreads();
    for (int off = 1; off < 1024; off <<= 1) {
        int x = (t >= off) ? buf[t - off] : 0;
        __syncthreads();
        buf[t] += x;
        __syncthreads();
    }
    if (t < nb) bexcl[t] = buf[t] - v;
    if (t == 1023) out[n] = buf[1023];
}

__global__ void k_scan_out(const int* __restrict__ in, const int* __restrict__ bexcl,
                           int* __restrict__ out, int n) {
    __shared__ int buf[256];
    int i = blockIdx.x * 256 + threadIdx.x;
    int t = threadIdx.x;
    int v = (i < n) ? in[i] : 0;
    buf[t] = v;
    __syncthreads();
    for (int off = 1; off < 256; off <<= 1) {
        int x = (t >= off) ? buf[t - off] : 0;
        __syncthreads();
        buf[t] += x;
        __syncthreads();
    }
    if (i < n) out[i] = bexcl[blockIdx.x] + buf[t] - v;
}

__global__ void k_fill_csr(const int* __restrict__ src, const int* __restrict__ dst,
                           const int* __restrict__ eoff, int* __restrict__ cursor,
                           int* __restrict__ csr, int n) {
    int e = blockIdx.x * blockDim.x + threadIdx.x;
    if (e < n) {
        int d = dst[e];
        int p = atomicAdd(&cursor[d], 1);
        csr[eoff[d] + p] = src[e];
    }
}

// ---------------- converts ----------------
__global__ void k_cvt16(const float* __restrict__ in, _Float16* __restrict__ out, int n4) {
    int i = blockIdx.x * blockDim.x + threadIdx.x;
    if (i < n4) {
        float4 v = *(const float4*)&in[i * 4];
        f16x4 o = { (_Float16)v.x, (_Float16)v.y, (_Float16)v.z, (_Float16)v.w };
        *(f16x4*)&out[i * 4] = o;
    }
}

// transpose + convert: Wt[l][n][k] = (fp16) W[l][k][n]
__global__ void k_wt(const float* __restrict__ W, _Float16* __restrict__ Wt, int K, int N) {
    __shared__ float tile[32][33];
    size_t mat = (size_t)K * N;
    W += blockIdx.z * mat;
    Wt += blockIdx.z * mat;
    int n0 = blockIdx.x * 32, k0 = blockIdx.y * 32;
    for (int i = threadIdx.y; i < 32; i += 8)
        tile[i][threadIdx.x] = W[(size_t)(k0 + i) * N + n0 + threadIdx.x];
    __syncthreads();
    for (int i = threadIdx.y; i < 32; i += 8)
        Wt[(size_t)(n0 + i) * K + k0 + threadIdx.x] = (_Float16)tile[threadIdx.x][i];
}

// ---------------- pooling / aggregation ----------------
__global__ void k_pool16(const _Float16* __restrict__ h16, const int* __restrict__ goff,
                         _Float16* __restrict__ pool) {
    int g = blockIdx.x;
    int c = threadIdx.x;
    int s = goff[g], e = goff[g + 1];
    float acc = 0.f;
    for (int r = s; r < e; ++r) acc += (float)h16[(size_t)r * HD + c];
    int cnt = e - s;
    pool[g * HD + c] = (_Float16)(acc / (float)(cnt > 0 ? cnt : 1));
}

// one wave per node; WAVE-UNIFORM loop bounds; 8 edges/iter
__global__ __launch_bounds__(256) void k_agg16(const _Float16* __restrict__ h16,
                                               const int* __restrict__ eoff,
                                               const int* __restrict__ csr,
                                               _Float16* __restrict__ out) {
    int node = blockIdx.x * 4 + (threadIdx.x >> 6);
    int lane = threadIdx.x & 63;
    int half = lane >> 5, l = lane & 31;
    f16x8 mine = *(const f16x8*)&h16[(size_t)node * HD + l * 8];
    float acc[8];
#pragma unroll
    for (int q = 0; q < 8; ++q) acc[q] = half ? 0.f : (float)mine[q];
    int s = eoff[node], e = eoff[node + 1];
    for (int base = s; base < e; base += 64) {
        int myi = base + lane;
        int vidx = (myi < e) ? csr[myi] : 0;
        int cnt = min(64, e - base);
        int jj = 0;
        for (; jj + 7 < cnt; jj += 8) {
            int s0 = __shfl(vidx, jj + half);
            int s1 = __shfl(vidx, jj + 2 + half);
            int s2 = __shfl(vidx, jj + 4 + half);
            int s3 = __shfl(vidx, jj + 6 + half);
            f16x8 v0 = *(const f16x8*)&h16[(size_t)s0 * HD + l * 8];
            f16x8 v1 = *(const f16x8*)&h16[(size_t)s1 * HD + l * 8];
            f16x8 v2 = *(const f16x8*)&h16[(size_t)s2 * HD + l * 8];
            f16x8 v3 = *(const f16x8*)&h16[(size_t)s3 * HD + l * 8];
#pragma unroll
            for (int q = 0; q < 8; ++q)
                acc[q] += ((float)v0[q] + (float)v1[q]) + ((float)v2[q] + (float)v3[q]);
        }
        for (; jj + 3 < cnt; jj += 4) {
            int s0 = __shfl(vidx, jj + half);
            int s1 = __shfl(vidx, jj + 2 + half);
            f16x8 v0 = *(const f16x8*)&h16[(size_t)s0 * HD + l * 8];
            f16x8 v1 = *(const f16x8*)&h16[(size_t)s1 * HD + l * 8];
#pragma unroll
            for (int q = 0; q < 8; ++q) acc[q] += (float)v0[q] + (float)v1[q];
        }
        for (; jj < cnt; jj += 2) {
            int i0 = jj + half;
            int s0 = __shfl(vidx, i0);
            if (i0 < cnt) {
                f16x8 v0 = *(const f16x8*)&h16[(size_t)s0 * HD + l * 8];
#pragma unroll
                for (int q = 0; q < 8; ++q) acc[q] += (float)v0[q];
            }
        }
    }
#pragma unroll
    for (int q = 0; q < 8; ++q) acc[q] += __shfl_xor(acc[q], 32);
    if (!half) {
        f16x8 o;
#pragma unroll
        for (int q = 0; q < 8; ++q) o[q] = (_Float16)acc[q];
        *(f16x8*)&out[(size_t)node * HD + l * 8] = o;
    }
}

// ---------------- batch norm finalize (also re-zeroes stat for next layer) ----
__global__ void k_bn_final(float* __restrict__ stat,
                           const float* __restrict__ gamma, const float* __restrict__ beta,
                           float* __restrict__ scale, float* __restrict__ shift) {
    int c = threadIdx.x;
    float mu = stat[c] * (1.0f / NN);
    float var = stat[HD + c] * (1.0f / NN) - mu * mu;
    float rs = rsqrtf(var + 1e-5f);
    float sc = rs * gamma[c];
    scale[c] = sc;
    shift[c] = beta[c] - mu * sc;
    stat[c] = 0.f;
    stat[HD + c] = 0.f;
}

__device__ __forceinline__ void bnpack(float4 g0, float4 g1, float4 s0, float4 s1,
                                       float4 h0, float4 h1, float4 o0, float4 o1, f16x8& r) {
    r[0] = (_Float16)(g0.x * s0.x + h0.x + o0.x);
    r[1] = (_Float16)(g0.y * s0.y + h0.y + o0.y);
    r[2] = (_Float16)(g0.z * s0.z + h0.z + o0.z);
    r[3] = (_Float16)(g0.w * s0.w + h0.w + o0.w);
    r[4] = (_Float16)(g1.x * s1.x + h1.x + o1.x);
    r[5] = (_Float16)(g1.y * s1.y + h1.y + o1.y);
    r[6] = (_Float16)(g1.z * s1.z + h1.z + o1.z);
    r[7] = (_Float16)(g1.w * s1.w + h1.w + o1.w);
}

// ---------------- MFMA fp16 GEMM (128x128 tile, double-buffered) ----------------
// RES: +R (fp32). RESBN: +R*bnsc+bnsh. BIAS2: +bias2[n]. STATS: fused BN stats.
// ABN: A-operand is fp32 A32 transformed on-stage: a = A32*bnsc+bnsh + ovn[batch[row]]
template <bool GELU, bool RES, bool RESBN, bool BIAS2, bool STATS, bool ABN, bool O32, bool O16>
__global__ __launch_bounds__(256) void k_mgemm(const _Float16* __restrict__ A,
                                               const float* __restrict__ A32,
                                               const _Float16* __restrict__ Wt,
                                               const float* __restrict__ bias,
                                               const float* __restrict__ bias2,
                                               const float* __restrict__ R,
                                               const float* __restrict__ bnsc,
                                               const float* __restrict__ bnsh,
                                               const float* __restrict__ ovn,
                                               const int* __restrict__ batchv,
                                               float* __restrict__ stat,
                                               float* __restrict__ C32,
                                               _Float16* __restrict__ C16,
                                               int M, int N, int K) {
    __shared__ _Float16 As[2][4][128][8];
    __shared__ _Float16 Bs[2][4][128][8];
    const int t = threadIdx.x;
    const int w = t >> 6, lane = t & 63;
    const int wr = w & 1, wc = w >> 1;
    const int m0 = blockIdx.y * 128, n0 = blockIdx.x * 128;
    const int kb = lane >> 4, fr = lane & 15;

    f32x4 acc[4][4];
#pragma unroll
    for (int mi = 0; mi < 4; ++mi)
#pragma unroll
        for (int ni = 0; ni < 4; ++ni) acc[mi][ni] = (f32x4){0.f, 0.f, 0.f, 0.f};

    const _Float16* gA0 = nullptr;
    const _Float16* gA1 = nullptr;
    int b0 = 0, b1r = 0;
    if constexpr (!ABN) {
        gA0 = A + (size_t)(m0 + lane) * K + w * 8;
        gA1 = A + (size_t)(m0 + 64 + lane) * K + w * 8;
    } else {
        b0 = batchv[min(m0 + lane, M - 1)];
        b1r = batchv[min(m0 + 64 + lane, M - 1)];
    }
    const _Float16* gB0 = Wt + (size_t)(n0 + lane) * K + w * 8;
    const _Float16* gB1 = Wt + (size_t)(n0 + 64 + lane) * K + w * 8;

    auto stage = [&](int buf, int k0) {
        if constexpr (ABN) {
            const int c0 = k0 + w * 8;
            float4 s0 = *(const float4*)&bnsc[c0];
            float4 s1 = *(const float4*)&bnsc[c0 + 4];
            float4 h0 = *(const float4*)&bnsh[c0];
            float4 h1 = *(const float4*)&bnsh[c0 + 4];
            const float* ga = A32 + (size_t)(m0 + lane) * K + c0;
            const float* gb = A32 + (size_t)(m0 + 64 + lane) * K + c0;
            float4 ga0 = *(const float4*)ga;
            float4 ga1 = *(const float4*)(ga + 4);
            float4 gb0 = *(const float4*)gb;
            float4 gb1 = *(const float4*)(gb + 4);
            float4 oa0 = *(const float4*)&ovn[(size_t)b0 * K + c0];
            float4 oa1 = *(const float4*)&ovn[(size_t)b0 * K + c0 + 4];
            float4 ob0 = *(const float4*)&ovn[(size_t)b1r * K + c0];
            float4 ob1 = *(const float4*)&ovn[(size_t)b1r * K + c0 + 4];
            f16x8 r0, r1;
            bnpack(ga0, ga1, s0, s1, h0, h1, oa0, oa1, r0);
            bnpack(gb0, gb1, s0, s1, h0, h1, ob0, ob1, r1);
            *(f16x8*)&As[buf][w][lane][0] = r0;
            *(f16x8*)&As[buf][w][64 + lane][0] = r1;
        } else {
            gl_lds16(gA0 + k0, &As[buf][w][0][0]);
            gl_lds16(gA1 + k0, &As[buf][w][64][0]);
        }
        gl_lds16(gB0 + k0, &Bs[buf][w][0][0]);
        gl_lds16(gB1 + k0, &Bs[buf][w][64][0]);
    };

    const int nt = K >> 5;
    stage(0, 0);
    __syncthreads();
    for (int tt = 0; tt < nt; ++tt) {
        const int cur = tt & 1;
        if (tt + 1 < nt) stage(cur ^ 1, (tt + 1) << 5);
        f16x8 af[4], bf[4];
#pragma unroll
        for (int mi = 0; mi < 4; ++mi)
            af[mi] = *(const f16x8*)&As[cur][kb][wr * 64 + mi * 16 + fr][0];
#pragma unroll
        for (int ni = 0; ni < 4; ++ni)
            bf[ni] = *(const f16x8*)&Bs[cur][kb][wc * 64 + ni * 16 + fr][0];
#pragma unroll
        for (int mi = 0; mi < 4; ++mi)
#pragma unroll
            for (int ni = 0; ni < 4; ++ni)
                acc[mi][ni] = __builtin_amdgcn_mfma_f32_16x16x32_f16(af[mi], bf[ni], acc[mi][ni], 0, 0, 0);
        __syncthreads();
    }

    const int rr = lane >> 4;
    float cs[4] = {0.f, 0.f, 0.f, 0.f}, cq[4] = {0.f, 0.f, 0.f, 0.f};
#pragma unroll
    for (int mi = 0; mi < 4; ++mi) {
#pragma unroll
        for (int reg = 0; reg < 4; ++reg) {
            int m = m0 + wr * 64 + mi * 16 + rr * 4 + reg;
            if (m < M) {
#pragma unroll
                for (int ni = 0; ni < 4; ++ni) {
                    int n = n0 + wc * 64 + ni * 16 + fr;
                    float v = acc[mi][ni][reg] + bias[n];
                    if (BIAS2) v += bias2[n];
                    if (GELU) v = gelu_exact(v);
                    if (RES) v += R[(size_t)m * N + n];
                    if (RESBN) v += R[(size_t)m * N + n] * bnsc[n] + bnsh[n];
                    if (O32) C32[(size_t)m * N + n] = v;
                    if (O16) C16[(size_t)m * N + n] = (_Float16)v;
                    if (STATS) { cs[ni] += v; cq[ni] += v * v; }
                }
            }
        }
    }
    if constexpr (STATS) {
        __shared__ float sred[2][128], qred[2][128];
#pragma unroll
        for (int ni = 0; ni < 4; ++ni) {
            cs[ni] += __shfl_xor(cs[ni], 16); cs[ni] += __shfl_xor(cs[ni], 32);
            cq[ni] += __shfl_xor(cq[ni], 16); cq[ni] += __shfl_xor(cq[ni], 32);
        }
        if (rr == 0) {
#pragma unroll
            for (int ni = 0; ni < 4; ++ni) {
                sred[wr][wc * 64 + ni * 16 + fr] = cs[ni];
                qred[wr][wc * 64 + ni * 16 + fr] = cq[ni];
            }
        }
        __syncthreads();
        if (t < 128) {
            atomicAdd(&stat[n0 + t], sred[0][t] + sred[1][t]);
            atomicAdd(&stat[HD + n0 + t], qred[0][t] + qred[1][t]);
        }
    }
}

// helpers
static inline void mg_gelu(hipStream_t st, const _Float16* A, const _Float16* Wt,
                           const float* bias, _Float16* C16, int M, int N, int K) {
    dim3 g(N / 128, (M + 127) / 128), b(256);
    k_mgemm<true, false, false, false, false, false, false, true><<<g, b, 0, st>>>(
        A, nullptr, Wt, bias, nullptr, nullptr, nullptr, nullptr, nullptr, nullptr, nullptr, nullptr, C16, M, N, K);
}
static inline void mg_both(hipStream_t st, const _Float16* A, const _Float16* Wt,
                           const float* bias, float* C32, _Float16* C16, int M, int N, int K) {
    dim3 g(N / 128, (M + 127) / 128), b(256);
    k_mgemm<false, false, false, false, false, false, true, true><<<g, b, 0, st>>>(
        A, nullptr, Wt, bias, nullptr, nullptr, nullptr, nullptr, nullptr, nullptr, nullptr, C32, C16, M, N, K);
}
static inline void mg_res32_stats(hipStream_t st, const _Float16* A, const _Float16* Wt,
                                  const float* bias, const float* R, float* stat,
                                  float* C32, int M, int N, int K) {
    dim3 g(N / 128, (M + 127) / 128), b(256);
    k_mgemm<false, true, false, false, true, false, true, false><<<g, b, 0, st>>>(
        A, nullptr, Wt, bias, nullptr, R, nullptr, nullptr, nullptr, nullptr, stat, C32, nullptr, M, N, K);
}
static inline void mg_gelu_abn(hipStream_t st, const float* A32, const _Float16* Wt,
                               const float* bias, const float* bnsc, const float* bnsh,
                               const float* ovn, const int* batchv, _Float16* C16,
                               int M, int N, int K) {
    dim3 g(N / 128, (M + 127) / 128), b(256);
    k_mgemm<true, false, false, false, false, true, false, true><<<g, b, 0, st>>>(
        nullptr, A32, Wt, bias, nullptr, nullptr, bnsc, bnsh, ovn, batchv, nullptr, nullptr, C16, M, N, K);
}
static inline void mg_resbn_both(hipStream_t st, const _Float16* A, const _Float16* Wt,
                                 const float* bias, const float* R, const float* bnsc,
                                 const float* bnsh, float* C32, _Float16* C16,
                                 int M, int N, int K) {
    dim3 g(N / 128, (M + 127) / 128), b(256);
    k_mgemm<false, false, true, false, false, false, true, true><<<g, b, 0, st>>>(
        A, nullptr, Wt, bias, nullptr, R, bnsc, bnsh, nullptr, nullptr, nullptr, C32, C16, M, N, K);
}
static inline void mg_bias2_16(hipStream_t st, const _Float16* A, const _Float16* Wt,
                               const float* bias, const float* bias2, _Float16* C16,
                               int M, int N, int K) {
    dim3 g(N / 128, (M + 127) / 128), b(256);
    k_mgemm<false, false, false, true, false, false, false, true><<<g, b, 0, st>>>(
        A, nullptr, Wt, bias, bias2, nullptr, nullptr, nullptr, nullptr, nullptr, nullptr, nullptr, C16, M, N, K);
}
static inline void mg_f32only(hipStream_t st, const _Float16* A, const _Float16* Wt,
                              const float* bias, float* C32, int M, int N, int K) {
    dim3 g(N / 128, (M + 127) / 128), b(256);
    k_mgemm<false, false, false, false, false, false, true, false><<<g, b, 0, st>>>(
        A, nullptr, Wt, bias, nullptr, nullptr, nullptr, nullptr, nullptr, nullptr, nullptr, C32, nullptr, M, N, K);
}

extern "C" void kernel_launch(void* const* d_in, const int* in_sizes, int n_in,
                              void* d_out, int out_size, void* d_ws, size_t ws_size,
                              hipStream_t stream) {
    const float* x       = (const float*)d_in[0];
    const int*   ei      = (const int*)d_in[1];
    const int*   batch   = (const int*)d_in[2];
    const float* pre_W1  = (const float*)d_in[3];
    const float* pre_b1  = (const float*)d_in[4];
    const float* pre_W2  = (const float*)d_in[5];
    const float* pre_b2  = (const float*)d_in[6];
    const float* gin_W1  = (const float*)d_in[7];
    const float* gin_b1  = (const float*)d_in[8];
    const float* gin_W2  = (const float*)d_in[9];
    const float* gin_b2  = (const float*)d_in[10];
    const float* ffn_W1  = (const float*)d_in[11];
    const float* ffn_b1  = (const float*)d_in[12];
    const float* ffn_W2  = (const float*)d_in[13];
    const float* ffn_b2  = (const float*)d_in[14];
    const float* upd_W1  = (const float*)d_in[15];
    const float* upd_b1  = (const float*)d_in[16];
    const float* upd_W2  = (const float*)d_in[17];
    const float* upd_b2  = (const float*)d_in[18];
    const float* prop_W1 = (const float*)d_in[19];
    const float* prop_b1 = (const float*)d_in[20];
    const float* prop_W2 = (const float*)d_in[21];
    const float* prop_b2 = (const float*)d_in[22];
    const float* bn_gamma= (const float*)d_in[23];
    const float* bn_beta = (const float*)d_in[24];
    const float* vn      = (const float*)d_in[25];
    const float* post_W1 = (const float*)d_in[26];
    const float* post_b1 = (const float*)d_in[27];
    const float* post_W2 = (const float*)d_in[28];
    const float* post_b2 = (const float*)d_in[29];
    float* out = (float*)d_out;

    const int* e_src = ei;
    const int* e_dst = ei + NE;

    // ---------- workspace layout ----------
    char* p = (char*)d_ws;
    auto alloc = [&](size_t bytes) -> char* {
        char* r = p;
        p += (bytes + 255) & ~(size_t)255;
        return r;
    };
    float*    h32    = (float*)alloc((size_t)NNP * HD * 4);   // fp32 backbone
    float*    g32    = (float*)alloc((size_t)NNP * HD * 4);   // gin2 out (raw)
    _Float16* h16    = (_Float16*)alloc((size_t)NNP * HD * 2);
    _Float16* t16a   = (_Float16*)alloc((size_t)NNP * HD * 2);
    _Float16* t16b   = (_Float16*)alloc((size_t)NNP * HD * 2);  // aliases x16 pre-launch
    _Float16* pool16 = (_Float16*)alloc((size_t)NG * HD * 2);
    _Float16* u16    = (_Float16*)alloc((size_t)NG * HD * 2);
    _Float16* vb16   = (_Float16*)alloc((size_t)NG * H4 * 2);
    _Float16* p16    = (_Float16*)alloc((size_t)NG * HD * 2);
    float*    outvn32= (float*)alloc((size_t)NG * HD * 4);
    float*    bnstat = (float*)alloc(2 * HD * 4);
    float*    bnscale= (float*)alloc(HD * 4);
    float*    bnshift= (float*)alloc(HD * 4);
    _Float16* preW1t = (_Float16*)alloc((size_t)HD * DIN * 2);
    _Float16* preW2t = (_Float16*)alloc((size_t)HD * HD * 2);
    _Float16* ginW1t = (_Float16*)alloc((size_t)NL * HD * HD * 2);
    _Float16* ginW2t = (_Float16*)alloc((size_t)NL * HD * HD * 2);
    _Float16* ffnW1t = (_Float16*)alloc((size_t)NL * HD * HD * 2);
    _Float16* ffnW2t = (_Float16*)alloc((size_t)NL * HD * HD * 2);
    _Float16* updW1t = (_Float16*)alloc((size_t)NL * HD * HD * 2);
    _Float16* updW2t = (_Float16*)alloc((size_t)NL * HD * H4 * 2);
    _Float16* propW1t= (_Float16*)alloc((size_t)NL * H4 * HD * 2);
    _Float16* propW2t= (_Float16*)alloc((size_t)NL * HD * HD * 2);
    _Float16* postW1t= (_Float16*)alloc((size_t)HD * HD * 2);
    _Float16* postW2t= (_Float16*)alloc((size_t)DOUT * HD * 2);
    int* gcount = (int*)alloc(NG * 4);
    int* goff   = (int*)alloc((NG + 1) * 4);
    int* deg    = (int*)alloc(NN * 4);
    int* eoff   = (int*)alloc((NN + 1) * 4);
    int* cursor = (int*)alloc(NN * 4);
    int* csr    = (int*)alloc((size_t)NE * 4);
    int* bsum   = (int*)alloc(1024 * 4);
    int* bexcl  = (int*)alloc(1024 * 4);
    _Float16* x16 = t16b;  // alias: only live before pre-GEMM1

    // ---------- zero counters (gcount..cursor contiguous span) + bnstat ----------
    {
        size_t span = (size_t)((char*)(cursor + NN) - (char*)gcount);
        hipMemsetAsync(gcount, 0, span, stream);
        hipMemsetAsync(bnstat, 0, 2 * HD * 4, stream);
    }
    hipLaunchKernelGGL(k_hist, dim3((NN + 255) / 256), dim3(256), 0, stream, batch, gcount, NN);
    hipLaunchKernelGGL(k_hist, dim3((NE + 255) / 256), dim3(256), 0, stream, e_dst, deg, NE);
    {
        int nbG = (NG + 255) / 256;
        hipLaunchKernelGGL(k_scan_part, dim3(nbG), dim3(256), 0, stream, gcount, bsum, NG);
        hipLaunchKernelGGL(k_scan_mid, dim3(1), dim3(1024), 0, stream, bsum, bexcl, nbG, goff, NG);
        hipLaunchKernelGGL(k_scan_out, dim3(nbG), dim3(256), 0, stream, gcount, bexcl, goff, NG);
        int nbN = (NN + 255) / 256;
        hipLaunchKernelGGL(k_scan_part, dim3(nbN), dim3(256), 0, stream, deg, bsum, NN);
        hipLaunchKernelGGL(k_scan_mid, dim3(1), dim3(1024), 0, stream, bsum, bexcl, nbN, eoff, NN);
        hipLaunchKernelGGL(k_scan_out, dim3(nbN), dim3(256), 0, stream, deg, bexcl, eoff, NN);
    }
    hipLaunchKernelGGL(k_fill_csr, dim3((NE + 255) / 256), dim3(256), 0, stream, e_src, e_dst, eoff, cursor, csr, NE);

    // ---------- weight convert + transpose ----------
    dim3 tb(32, 8);
    hipLaunchKernelGGL(k_wt, dim3(HD / 32, DIN / 32, 1), tb, 0, stream, pre_W1, preW1t, DIN, HD);
    hipLaunchKernelGGL(k_wt, dim3(HD / 32, HD / 32, 1), tb, 0, stream, pre_W2, preW2t, HD, HD);
    hipLaunchKernelGGL(k_wt, dim3(HD / 32, HD / 32, NL), tb, 0, stream, gin_W1, ginW1t, HD, HD);
    hipLaunchKernelGGL(k_wt, dim3(HD / 32, HD / 32, NL), tb, 0, stream, gin_W2, ginW2t, HD, HD);
    hipLaunchKernelGGL(k_wt, dim3(HD / 32, HD / 32, NL), tb, 0, stream, ffn_W1, ffnW1t, HD, HD);
    hipLaunchKernelGGL(k_wt, dim3(HD / 32, HD / 32, NL), tb, 0, stream, ffn_W2, ffnW2t, HD, HD);
    hipLaunchKernelGGL(k_wt, dim3(HD / 32, HD / 32, NL), tb, 0, stream, upd_W1, updW1t, HD, HD);
    hipLaunchKernelGGL(k_wt, dim3(H4 / 32, HD / 32, NL), tb, 0, stream, upd_W2, updW2t, HD, H4);
    hipLaunchKernelGGL(k_wt, dim3(HD / 32, H4 / 32, NL), tb, 0, stream, prop_W1, propW1t, H4, HD);
    hipLaunchKernelGGL(k_wt, dim3(HD / 32, HD / 32, NL), tb, 0, stream, prop_W2, propW2t, HD, HD);
    hipLaunchKernelGGL(k_wt, dim3(HD / 32, HD / 32, 1), tb, 0, stream, post_W1, postW1t, HD, HD);
    hipLaunchKernelGGL(k_wt, dim3(DOUT / 32, HD / 32, 1), tb, 0, stream, post_W2, postW2t, HD, DOUT);

    // x -> fp16
    int n4 = NN * DIN / 4;
    hipLaunchKernelGGL(k_cvt16, dim3((n4 + 255) / 256), dim3(256), 0, stream, x, x16, n4);

    // ---------- pre-FFNN ----------
    mg_gelu(stream, x16, preW1t, pre_b1, t16a, NN, HD, DIN);
    mg_both(stream, t16a, preW2t, pre_b2, h32, h16, NN, HD, HD);

    for (int i = 0; i < NL; ++i) {
        const _Float16* uW1 = updW1t + (size_t)i * HD * HD;
        const _Float16* uW2 = updW2t + (size_t)i * HD * H4;
        const _Float16* pW1 = propW1t + (size_t)i * H4 * HD;
        const _Float16* pW2 = propW2t + (size_t)i * HD * HD;
        const _Float16* gW1 = ginW1t + (size_t)i * HD * HD;
        const _Float16* gW2 = ginW2t + (size_t)i * HD * HD;
        const _Float16* fW1 = ffnW1t + (size_t)i * HD * HD;
        const _Float16* fW2 = ffnW2t + (size_t)i * HD * HD;

        // virtual-node path (M = NG = 512) via MFMA GEMMs
        hipLaunchKernelGGL(k_pool16, dim3(NG), dim3(HD), 0, stream, h16, goff, pool16);
        mg_gelu(stream, pool16, uW1, upd_b1 + (size_t)i * HD, u16, NG, HD, HD);
        mg_bias2_16(stream, u16, uW2, upd_b2 + (size_t)i * H4, vn, vb16, NG, H4, HD);
        mg_gelu(stream, vb16, pW1, prop_b1 + (size_t)i * HD, p16, NG, HD, H4);
        mg_f32only(stream, p16, pW2, prop_b2 + (size_t)i * HD, outvn32, NG, HD, HD);

        // GIN: t16a = agg(h16); t16b = gelu(t16a@W1+b); g32 = t16b@W2+b + h32 (+fused BN stats)
        hipLaunchKernelGGL(k_agg16, dim3(NN / 4), dim3(256), 0, stream, h16, eoff, csr, t16a);
        mg_gelu(stream, t16a, gW1, gin_b1 + (size_t)i * HD, t16b, NN, HD, HD);
        mg_res32_stats(stream, t16b, gW2, gin_b2 + (size_t)i * HD, h32, bnstat, g32, NN, HD, HD);

        // BN finalize (re-zeroes stat)
        hipLaunchKernelGGL(k_bn_final, dim3(1), dim3(HD), 0, stream, bnstat,
                           bn_gamma + (size_t)i * HD, bn_beta + (size_t)i * HD, bnscale, bnshift);

        // FFN1 with fused BN+VN A-transform: t16b = gelu((bn(g32)+ovn)@fW1+b)
        mg_gelu_abn(stream, g32, fW1, ffn_b1 + (size_t)i * HD, bnscale, bnshift,
                    outvn32, batch, t16b, NN, HD, HD);
        // FFN2: h32/h16 = t16b@fW2+b + (g32*scale+shift)
        mg_resbn_both(stream, t16b, fW2, ffn_b2 + (size_t)i * HD, g32, bnscale, bnshift,
                      h32, h16, NN, HD, HD);
    }

    // ---------- post ----------
    hipLaunchKernelGGL(k_pool16, dim3(NG), dim3(HD), 0, stream, h16, goff, pool16);
    mg_gelu(stream, pool16, postW1t, post_b1, u16, NG, HD, HD);
    mg_f32only(stream, u16, postW2t, post_b2, out, NG, DOUT, HD);
}

// Round 9
// 1964.526 us; speedup vs baseline: 1.2165x; 1.1258x over previous
//
#include <hip/hip_runtime.h>
#include <hip/hip_bf16.h>
#include <math.h>

#define NN 50000
#define NNP 50048          // padded to multiple of 128
#define NE 800000
#define NG 512
#define DIN 128
#define HD 256
#define DOUT 128
#define NL 5
#define H4 1024

typedef _Float16 f16x8 __attribute__((ext_vector_type(8)));
typedef _Float16 f16x4 __attribute__((ext_vector_type(4)));
typedef float f32x4 __attribute__((ext_vector_type(4)));

__device__ __forceinline__ float gelu_exact(float x) {
    return 0.5f * x * (1.0f + erff(x * 0.70710678118654752f));
}

__device__ __forceinline__ void gl_lds16(const _Float16* g, _Float16* l) {
    __builtin_amdgcn_global_load_lds(
        (const __attribute__((address_space(1))) unsigned int*)g,
        (__attribute__((address_space(3))) unsigned int*)l, 16, 0, 0);
}

// ---------------- graph meta ----------------
__global__ void k_hist(const int* __restrict__ idx, int* __restrict__ cnt, int n) {
    int i = blockIdx.x * blockDim.x + threadIdx.x;
    if (i < n) atomicAdd(&cnt[idx[i]], 1);
}

// single-block exclusive scan for n <= 1024 (writes out[n] = total)
__global__ void k_scan_small(const int* __restrict__ in, int* __restrict__ out, int n) {
    __shared__ int buf[1024];
    int t = threadIdx.x;
    int v = (t < n) ? in[t] : 0;
    buf[t] = v;
    __syncthreads();
    for (int off = 1; off < 1024; off <<= 1) {
        int x = (t >= off) ? buf[t - off] : 0;
        __syncthreads();
        buf[t] += x;
        __syncthreads();
    }
    if (t < n) out[t] = buf[t] - v;
    if (t == 1023) out[n] = buf[1023];
}

__global__ void k_scan_part(const int* __restrict__ in, int* __restrict__ bsum, int n) {
    __shared__ int buf[256];
    int i = blockIdx.x * 256 + threadIdx.x;
    buf[threadIdx.x] = (i < n) ? in[i] : 0;
    __syncthreads();
    for (int off = 128; off > 0; off >>= 1) {
        if (threadIdx.x < off) buf[threadIdx.x] += buf[threadIdx.x + off];
        __syncthreads();
    }
    if (threadIdx.x == 0) bsum[blockIdx.x] = buf[0];
}

__global__ void k_scan_mid(const int* __restrict__ bsum, int* __restrict__ bexcl, int nb,
                           int* __restrict__ out, int n) {
    __shared__ int buf[1024];
    int t = threadIdx.x;
    int v = (t < nb) ? bsum[t] : 0;
    buf[t] = v;
    __syncthreads();
    for (int off = 1; off < 1024; off <<= 1) {
        int x = (t >= off) ? buf[t - off] : 0;
        __syncthreads();
        buf[t] += x;
        __syncthreads();
    }
    if (t < nb) bexcl[t] = buf[t] - v;
    if (t == 1023) out[n] = buf[1023];
}

__global__ void k_scan_out(const int* __restrict__ in, const int* __restrict__ bexcl,
                           int* __restrict__ out, int n) {
    __shared__ int buf[256];
    int i = blockIdx.x * 256 + threadIdx.x;
    int t = threadIdx.x;
    int v = (i < n) ? in[i] : 0;
    buf[t] = v;
    __syncthreads();
    for (int off = 1; off < 256; off <<= 1) {
        int x = (t >= off) ? buf[t - off] : 0;
        __syncthreads();
        buf[t] += x;
        __syncthreads();
    }
    if (i < n) out[i] = bexcl[blockIdx.x] + buf[t] - v;
}

__global__ void k_fill_csr(const int* __restrict__ src, const int* __restrict__ dst,
                           const int* __restrict__ eoff, int* __restrict__ cursor,
                           int* __restrict__ csr, int n) {
    int e = blockIdx.x * blockDim.x + threadIdx.x;
    if (e < n) {
        int d = dst[e];
        int p = atomicAdd(&cursor[d], 1);
        csr[eoff[d] + p] = src[e];
    }
}

// ---------------- converts ----------------
__global__ void k_cvt16(const float* __restrict__ in, _Float16* __restrict__ out, int n4) {
    int i = blockIdx.x * blockDim.x + threadIdx.x;
    if (i < n4) {
        float4 v = *(const float4*)&in[i * 4];
        f16x4 o = { (_Float16)v.x, (_Float16)v.y, (_Float16)v.z, (_Float16)v.w };
        *(f16x4*)&out[i * 4] = o;
    }
}

// transpose + convert: Wt[l][n][k] = (fp16) W[l][k][n]
__global__ void k_wt(const float* __restrict__ W, _Float16* __restrict__ Wt, int K, int N) {
    __shared__ float tile[32][33];
    size_t mat = (size_t)K * N;
    W += blockIdx.z * mat;
    Wt += blockIdx.z * mat;
    int n0 = blockIdx.x * 32, k0 = blockIdx.y * 32;
    for (int i = threadIdx.y; i < 32; i += 8)
        tile[i][threadIdx.x] = W[(size_t)(k0 + i) * N + n0 + threadIdx.x];
    __syncthreads();
    for (int i = threadIdx.y; i < 32; i += 8)
        Wt[(size_t)(n0 + i) * K + k0 + threadIdx.x] = (_Float16)tile[threadIdx.x][i];
}

// ---------------- pooling / aggregation ----------------
__global__ void k_pool16(const _Float16* __restrict__ h16, const int* __restrict__ goff,
                         _Float16* __restrict__ pool) {
    int g = blockIdx.x;
    int c = threadIdx.x;
    int s = goff[g], e = goff[g + 1];
    float acc = 0.f;
    for (int r = s; r < e; ++r) acc += (float)h16[(size_t)r * HD + c];
    int cnt = e - s;
    pool[g * HD + c] = (_Float16)(acc / (float)(cnt > 0 ? cnt : 1));
}

// one wave per node; WAVE-UNIFORM loop bounds; 8 edges/iter
__global__ __launch_bounds__(256) void k_agg16(const _Float16* __restrict__ h16,
                                               const int* __restrict__ eoff,
                                               const int* __restrict__ csr,
                                               _Float16* __restrict__ out) {
    int node = blockIdx.x * 4 + (threadIdx.x >> 6);
    int lane = threadIdx.x & 63;
    int half = lane >> 5, l = lane & 31;
    f16x8 mine = *(const f16x8*)&h16[(size_t)node * HD + l * 8];
    float acc[8];
#pragma unroll
    for (int q = 0; q < 8; ++q) acc[q] = half ? 0.f : (float)mine[q];
    int s = eoff[node], e = eoff[node + 1];
    for (int base = s; base < e; base += 64) {
        int myi = base + lane;
        int vidx = (myi < e) ? csr[myi] : 0;
        int cnt = min(64, e - base);
        int jj = 0;
        for (; jj + 7 < cnt; jj += 8) {
            int s0 = __shfl(vidx, jj + half);
            int s1 = __shfl(vidx, jj + 2 + half);
            int s2 = __shfl(vidx, jj + 4 + half);
            int s3 = __shfl(vidx, jj + 6 + half);
            f16x8 v0 = *(const f16x8*)&h16[(size_t)s0 * HD + l * 8];
            f16x8 v1 = *(const f16x8*)&h16[(size_t)s1 * HD + l * 8];
            f16x8 v2 = *(const f16x8*)&h16[(size_t)s2 * HD + l * 8];
            f16x8 v3 = *(const f16x8*)&h16[(size_t)s3 * HD + l * 8];
#pragma unroll
            for (int q = 0; q < 8; ++q)
                acc[q] += ((float)v0[q] + (float)v1[q]) + ((float)v2[q] + (float)v3[q]);
        }
        for (; jj + 3 < cnt; jj += 4) {
            int s0 = __shfl(vidx, jj + half);
            int s1 = __shfl(vidx, jj + 2 + half);
            f16x8 v0 = *(const f16x8*)&h16[(size_t)s0 * HD + l * 8];
            f16x8 v1 = *(const f16x8*)&h16[(size_t)s1 * HD + l * 8];
#pragma unroll
            for (int q = 0; q < 8; ++q) acc[q] += (float)v0[q] + (float)v1[q];
        }
        for (; jj < cnt; jj += 2) {
            int i0 = jj + half;
            int s0 = __shfl(vidx, i0);
            if (i0 < cnt) {
                f16x8 v0 = *(const f16x8*)&h16[(size_t)s0 * HD + l * 8];
#pragma unroll
                for (int q = 0; q < 8; ++q) acc[q] += (float)v0[q];
            }
        }
    }
#pragma unroll
    for (int q = 0; q < 8; ++q) acc[q] += __shfl_xor(acc[q], 32);
    if (!half) {
        f16x8 o;
#pragma unroll
        for (int q = 0; q < 8; ++q) o[q] = (_Float16)acc[q];
        *(f16x8*)&out[(size_t)node * HD + l * 8] = o;
    }
}

// ---------------- batch norm finalize (also re-zeroes stat for next layer) ----
__global__ void k_bn_final(float* __restrict__ stat,
                           const float* __restrict__ gamma, const float* __restrict__ beta,
                           float* __restrict__ scale, float* __restrict__ shift) {
    int c = threadIdx.x;
    float mu = stat[c] * (1.0f / NN);
    float var = stat[HD + c] * (1.0f / NN) - mu * mu;
    float rs = rsqrtf(var + 1e-5f);
    float sc = rs * gamma[c];
    scale[c] = sc;
    shift[c] = beta[c] - mu * sc;
    stat[c] = 0.f;
    stat[HD + c] = 0.f;
}

__device__ __forceinline__ void bnpack(float4 g0, float4 g1, float4 s0, float4 s1,
                                       float4 h0, float4 h1, float4 o0, float4 o1, f16x8& r) {
    r[0] = (_Float16)(g0.x * s0.x + h0.x + o0.x);
    r[1] = (_Float16)(g0.y * s0.y + h0.y + o0.y);
    r[2] = (_Float16)(g0.z * s0.z + h0.z + o0.z);
    r[3] = (_Float16)(g0.w * s0.w + h0.w + o0.w);
    r[4] = (_Float16)(g1.x * s1.x + h1.x + o1.x);
    r[5] = (_Float16)(g1.y * s1.y + h1.y + o1.y);
    r[6] = (_Float16)(g1.z * s1.z + h1.z + o1.z);
    r[7] = (_Float16)(g1.w * s1.w + h1.w + o1.w);
}

// ---------------- MFMA fp16 GEMM (64x128 tile, double-buffered) ----------------
// Tile: 64 rows x 128 cols, 4 waves (wave w owns cols w*32..w*32+31).
// RES: +R (fp32). RESBN: +R*bnsc+bnsh. BIAS2: +bias2[n]. STATS: fused BN stats.
// ABN: A-operand is fp32 A32 transformed on-stage: a = A32*bnsc+bnsh + ovn[batch[row]]
template <bool GELU, bool RES, bool RESBN, bool BIAS2, bool STATS, bool ABN, bool O32, bool O16>
__global__ __launch_bounds__(256) void k_mgemm(const _Float16* __restrict__ A,
                                               const float* __restrict__ A32,
                                               const _Float16* __restrict__ Wt,
                                               const float* __restrict__ bias,
                                               const float* __restrict__ bias2,
                                               const float* __restrict__ R,
                                               const float* __restrict__ bnsc,
                                               const float* __restrict__ bnsh,
                                               const float* __restrict__ ovn,
                                               const int* __restrict__ batchv,
                                               float* __restrict__ stat,
                                               float* __restrict__ C32,
                                               _Float16* __restrict__ C16,
                                               int M, int N, int K) {
    __shared__ _Float16 As[2][4][64][8];     // 8 KB
    __shared__ _Float16 Bs[2][4][128][8];    // 16 KB
    const int t = threadIdx.x;
    const int w = t >> 6, lane = t & 63;
    const int m0 = blockIdx.y * 64, n0 = blockIdx.x * 128;
    const int kb = lane >> 4, fr = lane & 15;

    f32x4 acc[4][2];
#pragma unroll
    for (int mi = 0; mi < 4; ++mi)
#pragma unroll
        for (int ni = 0; ni < 2; ++ni) acc[mi][ni] = (f32x4){0.f, 0.f, 0.f, 0.f};

    // A staging: gl_lds path -> wave w stages k-block w, row=lane
    //            ABN path    -> thread t stages row t&63, k-block t>>6
    const _Float16* gA0 = nullptr;
    int ar = 0, akb = 0, b0 = 0;
    if constexpr (!ABN) {
        gA0 = A + (size_t)(m0 + lane) * K + w * 8;
    } else {
        ar = t & 63;
        akb = t >> 6;
        b0 = batchv[min(m0 + ar, M - 1)];
    }
    const _Float16* gB0 = Wt + (size_t)(n0 + lane) * K + w * 8;
    const _Float16* gB1 = Wt + (size_t)(n0 + 64 + lane) * K + w * 8;

    auto stage = [&](int buf, int k0) {
        gl_lds16(gB0 + k0, &Bs[buf][w][0][0]);
        gl_lds16(gB1 + k0, &Bs[buf][w][64][0]);
        if constexpr (ABN) {
            const int c0 = k0 + akb * 8;
            float4 s0 = *(const float4*)&bnsc[c0];
            float4 s1 = *(const float4*)&bnsc[c0 + 4];
            float4 h0 = *(const float4*)&bnsh[c0];
            float4 h1 = *(const float4*)&bnsh[c0 + 4];
            const float* ga = A32 + (size_t)(m0 + ar) * K + c0;
            float4 ga0 = *(const float4*)ga;
            float4 ga1 = *(const float4*)(ga + 4);
            float4 oa0 = *(const float4*)&ovn[(size_t)b0 * K + c0];
            float4 oa1 = *(const float4*)&ovn[(size_t)b0 * K + c0 + 4];
            f16x8 r0;
            bnpack(ga0, ga1, s0, s1, h0, h1, oa0, oa1, r0);
            *(f16x8*)&As[buf][akb][ar][0] = r0;
        } else {
            gl_lds16(gA0 + k0, &As[buf][w][0][0]);
        }
    };

    const int nt = K >> 5;
    stage(0, 0);
    __syncthreads();
    for (int tt = 0; tt < nt; ++tt) {
        const int cur = tt & 1;
        if (tt + 1 < nt) stage(cur ^ 1, (tt + 1) << 5);
        f16x8 af[4], bf[2];
#pragma unroll
        for (int mi = 0; mi < 4; ++mi)
            af[mi] = *(const f16x8*)&As[cur][kb][mi * 16 + fr][0];
#pragma unroll
        for (int ni = 0; ni < 2; ++ni)
            bf[ni] = *(const f16x8*)&Bs[cur][kb][w * 32 + ni * 16 + fr][0];
#pragma unroll
        for (int mi = 0; mi < 4; ++mi)
#pragma unroll
            for (int ni = 0; ni < 2; ++ni)
                acc[mi][ni] = __builtin_amdgcn_mfma_f32_16x16x32_f16(af[mi], bf[ni], acc[mi][ni], 0, 0, 0);
        __syncthreads();
    }

    const int rr = lane >> 4;
    float cs[2] = {0.f, 0.f}, cq[2] = {0.f, 0.f};
#pragma unroll
    for (int mi = 0; mi < 4; ++mi) {
#pragma unroll
        for (int reg = 0; reg < 4; ++reg) {
            int m = m0 + mi * 16 + rr * 4 + reg;
            if (m < M) {
#pragma unroll
                for (int ni = 0; ni < 2; ++ni) {
                    int n = n0 + w * 32 + ni * 16 + fr;
                    float v = acc[mi][ni][reg] + bias[n];
                    if (BIAS2) v += bias2[n];
                    if (GELU) v = gelu_exact(v);
                    if (RES) v += R[(size_t)m * N + n];
                    if (RESBN) v += R[(size_t)m * N + n] * bnsc[n] + bnsh[n];
                    if (O32) C32[(size_t)m * N + n] = v;
                    if (O16) C16[(size_t)m * N + n] = (_Float16)v;
                    if (STATS) { cs[ni] += v; cq[ni] += v * v; }
                }
            }
        }
    }
    if constexpr (STATS) {
        // per-wave columns are disjoint; reduce over rr groups then one atomic per col
#pragma unroll
        for (int ni = 0; ni < 2; ++ni) {
            cs[ni] += __shfl_xor(cs[ni], 16); cs[ni] += __shfl_xor(cs[ni], 32);
            cq[ni] += __shfl_xor(cq[ni], 16); cq[ni] += __shfl_xor(cq[ni], 32);
        }
        if (lane < 16) {
#pragma unroll
            for (int ni = 0; ni < 2; ++ni) {
                int n = n0 + w * 32 + ni * 16 + lane;
                atomicAdd(&stat[n], cs[ni]);
                atomicAdd(&stat[HD + n], cq[ni]);
            }
        }
    }
}

// helpers
static inline void mg_gelu(hipStream_t st, const _Float16* A, const _Float16* Wt,
                           const float* bias, _Float16* C16, int M, int N, int K) {
    dim3 g(N / 128, (M + 63) / 64), b(256);
    k_mgemm<true, false, false, false, false, false, false, true><<<g, b, 0, st>>>(
        A, nullptr, Wt, bias, nullptr, nullptr, nullptr, nullptr, nullptr, nullptr, nullptr, nullptr, C16, M, N, K);
}
static inline void mg_both(hipStream_t st, const _Float16* A, const _Float16* Wt,
                           const float* bias, float* C32, _Float16* C16, int M, int N, int K) {
    dim3 g(N / 128, (M + 63) / 64), b(256);
    k_mgemm<false, false, false, false, false, false, true, true><<<g, b, 0, st>>>(
        A, nullptr, Wt, bias, nullptr, nullptr, nullptr, nullptr, nullptr, nullptr, nullptr, C32, C16, M, N, K);
}
static inline void mg_res32_stats(hipStream_t st, const _Float16* A, const _Float16* Wt,
                                  const float* bias, const float* R, float* stat,
                                  float* C32, int M, int N, int K) {
    dim3 g(N / 128, (M + 63) / 64), b(256);
    k_mgemm<false, true, false, false, true, false, true, false><<<g, b, 0, st>>>(
        A, nullptr, Wt, bias, nullptr, R, nullptr, nullptr, nullptr, nullptr, stat, C32, nullptr, M, N, K);
}
static inline void mg_gelu_abn(hipStream_t st, const float* A32, const _Float16* Wt,
                               const float* bias, const float* bnsc, const float* bnsh,
                               const float* ovn, const int* batchv, _Float16* C16,
                               int M, int N, int K) {
    dim3 g(N / 128, (M + 63) / 64), b(256);
    k_mgemm<true, false, false, false, false, true, false, true><<<g, b, 0, st>>>(
        nullptr, A32, Wt, bias, nullptr, nullptr, bnsc, bnsh, ovn, batchv, nullptr, nullptr, C16, M, N, K);
}
static inline void mg_resbn_both(hipStream_t st, const _Float16* A, const _Float16* Wt,
                                 const float* bias, const float* R, const float* bnsc,
                                 const float* bnsh, float* C32, _Float16* C16,
                                 int M, int N, int K) {
    dim3 g(N / 128, (M + 63) / 64), b(256);
    k_mgemm<false, false, true, false, false, false, true, true><<<g, b, 0, st>>>(
        A, nullptr, Wt, bias, nullptr, R, bnsc, bnsh, nullptr, nullptr, nullptr, C32, C16, M, N, K);
}
static inline void mg_bias2_16(hipStream_t st, const _Float16* A, const _Float16* Wt,
                               const float* bias, const float* bias2, _Float16* C16,
                               int M, int N, int K) {
    dim3 g(N / 128, (M + 63) / 64), b(256);
    k_mgemm<false, false, false, true, false, false, false, true><<<g, b, 0, st>>>(
        A, nullptr, Wt, bias, bias2, nullptr, nullptr, nullptr, nullptr, nullptr, nullptr, nullptr, C16, M, N, K);
}
static inline void mg_f32only(hipStream_t st, const _Float16* A, const _Float16* Wt,
                              const float* bias, float* C32, int M, int N, int K) {
    dim3 g(N / 128, (M + 63) / 64), b(256);
    k_mgemm<false, false, false, false, false, false, true, false><<<g, b, 0, st>>>(
        A, nullptr, Wt, bias, nullptr, nullptr, nullptr, nullptr, nullptr, nullptr, nullptr, C32, nullptr, M, N, K);
}

extern "C" void kernel_launch(void* const* d_in, const int* in_sizes, int n_in,
                              void* d_out, int out_size, void* d_ws, size_t ws_size,
                              hipStream_t stream) {
    const float* x       = (const float*)d_in[0];
    const int*   ei      = (const int*)d_in[1];
    const int*   batch   = (const int*)d_in[2];
    const float* pre_W1  = (const float*)d_in[3];
    const float* pre_b1  = (const float*)d_in[4];
    const float* pre_W2  = (const float*)d_in[5];
    const float* pre_b2  = (const float*)d_in[6];
    const float* gin_W1  = (const float*)d_in[7];
    const float* gin_b1  = (const float*)d_in[8];
    const float* gin_W2  = (const float*)d_in[9];
    const float* gin_b2  = (const float*)d_in[10];
    const float* ffn_W1  = (const float*)d_in[11];
    const float* ffn_b1  = (const float*)d_in[12];
    const float* ffn_W2  = (const float*)d_in[13];
    const float* ffn_b2  = (const float*)d_in[14];
    const float* upd_W1  = (const float*)d_in[15];
    const float* upd_b1  = (const float*)d_in[16];
    const float* upd_W2  = (const float*)d_in[17];
    const float* upd_b2  = (const float*)d_in[18];
    const float* prop_W1 = (const float*)d_in[19];
    const float* prop_b1 = (const float*)d_in[20];
    const float* prop_W2 = (const float*)d_in[21];
    const float* prop_b2 = (const float*)d_in[22];
    const float* bn_gamma= (const float*)d_in[23];
    const float* bn_beta = (const float*)d_in[24];
    const float* vn      = (const float*)d_in[25];
    const float* post_W1 = (const float*)d_in[26];
    const float* post_b1 = (const float*)d_in[27];
    const float* post_W2 = (const float*)d_in[28];
    const float* post_b2 = (const float*)d_in[29];
    float* out = (float*)d_out;

    const int* e_src = ei;
    const int* e_dst = ei + NE;

    // ---------- workspace layout ----------
    char* p = (char*)d_ws;
    auto alloc = [&](size_t bytes) -> char* {
        char* r = p;
        p += (bytes + 255) & ~(size_t)255;
        return r;
    };
    float*    h32    = (float*)alloc((size_t)NNP * HD * 4);   // fp32 backbone
    float*    g32    = (float*)alloc((size_t)NNP * HD * 4);   // gin2 out (raw)
    _Float16* h16    = (_Float16*)alloc((size_t)NNP * HD * 2);
    _Float16* t16a   = (_Float16*)alloc((size_t)NNP * HD * 2);
    _Float16* t16b   = (_Float16*)alloc((size_t)NNP * HD * 2);  // aliases x16 pre-launch
    _Float16* pool16 = (_Float16*)alloc((size_t)NG * HD * 2);
    _Float16* u16    = (_Float16*)alloc((size_t)NG * HD * 2);
    _Float16* vb16   = (_Float16*)alloc((size_t)NG * H4 * 2);
    _Float16* p16    = (_Float16*)alloc((size_t)NG * HD * 2);
    float*    outvn32= (float*)alloc((size_t)NG * HD * 4);
    float*    bnstat = (float*)alloc(2 * HD * 4);
    float*    bnscale= (float*)alloc(HD * 4);
    float*    bnshift= (float*)alloc(HD * 4);
    _Float16* preW1t = (_Float16*)alloc((size_t)HD * DIN * 2);
    _Float16* preW2t = (_Float16*)alloc((size_t)HD * HD * 2);
    _Float16* ginW1t = (_Float16*)alloc((size_t)NL * HD * HD * 2);
    _Float16* ginW2t = (_Float16*)alloc((size_t)NL * HD * HD * 2);
    _Float16* ffnW1t = (_Float16*)alloc((size_t)NL * HD * HD * 2);
    _Float16* ffnW2t = (_Float16*)alloc((size_t)NL * HD * HD * 2);
    _Float16* updW1t = (_Float16*)alloc((size_t)NL * HD * HD * 2);
    _Float16* updW2t = (_Float16*)alloc((size_t)NL * HD * H4 * 2);
    _Float16* propW1t= (_Float16*)alloc((size_t)NL * H4 * HD * 2);
    _Float16* propW2t= (_Float16*)alloc((size_t)NL * HD * HD * 2);
    _Float16* postW1t= (_Float16*)alloc((size_t)HD * HD * 2);
    _Float16* postW2t= (_Float16*)alloc((size_t)DOUT * HD * 2);
    int* gcount = (int*)alloc(NG * 4);
    int* goff   = (int*)alloc((NG + 1) * 4);
    int* deg    = (int*)alloc(NN * 4);
    int* eoff   = (int*)alloc((NN + 1) * 4);
    int* cursor = (int*)alloc(NN * 4);
    int* csr    = (int*)alloc((size_t)NE * 4);
    int* bsum   = (int*)alloc(1024 * 4);
    int* bexcl  = (int*)alloc(1024 * 4);
    _Float16* x16 = t16b;  // alias: only live before pre-GEMM1

    // ---------- zero counters (gcount..cursor contiguous span) + bnstat ----------
    {
        size_t span = (size_t)((char*)(cursor + NN) - (char*)gcount);
        hipMemsetAsync(gcount, 0, span, stream);
        hipMemsetAsync(bnstat, 0, 2 * HD * 4, stream);
    }
    hipLaunchKernelGGL(k_hist, dim3((NN + 255) / 256), dim3(256), 0, stream, batch, gcount, NN);
    hipLaunchKernelGGL(k_hist, dim3((NE + 255) / 256), dim3(256), 0, stream, e_dst, deg, NE);
    hipLaunchKernelGGL(k_scan_small, dim3(1), dim3(1024), 0, stream, gcount, goff, NG);
    {
        int nbN = (NN + 255) / 256;
        hipLaunchKernelGGL(k_scan_part, dim3(nbN), dim3(256), 0, stream, deg, bsum, NN);
        hipLaunchKernelGGL(k_scan_mid, dim3(1), dim3(1024), 0, stream, bsum, bexcl, nbN, eoff, NN);
        hipLaunchKernelGGL(k_scan_out, dim3(nbN), dim3(256), 0, stream, deg, bexcl, eoff, NN);
    }
    hipLaunchKernelGGL(k_fill_csr, dim3((NE + 255) / 256), dim3(256), 0, stream, e_src, e_dst, eoff, cursor, csr, NE);

    // ---------- weight convert + transpose ----------
    dim3 tb(32, 8);
    hipLaunchKernelGGL(k_wt, dim3(HD / 32, DIN / 32, 1), tb, 0, stream, pre_W1, preW1t, DIN, HD);
    hipLaunchKernelGGL(k_wt, dim3(HD / 32, HD / 32, 1), tb, 0, stream, pre_W2, preW2t, HD, HD);
    hipLaunchKernelGGL(k_wt, dim3(HD / 32, HD / 32, NL), tb, 0, stream, gin_W1, ginW1t, HD, HD);
    hipLaunchKernelGGL(k_wt, dim3(HD / 32, HD / 32, NL), tb, 0, stream, gin_W2, ginW2t, HD, HD);
    hipLaunchKernelGGL(k_wt, dim3(HD / 32, HD / 32, NL), tb, 0, stream, ffn_W1, ffnW1t, HD, HD);
    hipLaunchKernelGGL(k_wt, dim3(HD / 32, HD / 32, NL), tb, 0, stream, ffn_W2, ffnW2t, HD, HD);
    hipLaunchKernelGGL(k_wt, dim3(HD / 32, HD / 32, NL), tb, 0, stream, upd_W1, updW1t, HD, HD);
    hipLaunchKernelGGL(k_wt, dim3(H4 / 32, HD / 32, NL), tb, 0, stream, upd_W2, updW2t, HD, H4);
    hipLaunchKernelGGL(k_wt, dim3(HD / 32, H4 / 32, NL), tb, 0, stream, prop_W1, propW1t, H4, HD);
    hipLaunchKernelGGL(k_wt, dim3(HD / 32, HD / 32, NL), tb, 0, stream, prop_W2, propW2t, HD, HD);
    hipLaunchKernelGGL(k_wt, dim3(HD / 32, HD / 32, 1), tb, 0, stream, post_W1, postW1t, HD, HD);
    hipLaunchKernelGGL(k_wt, dim3(DOUT / 32, HD / 32, 1), tb, 0, stream, post_W2, postW2t, HD, DOUT);

    // x -> fp16
    int n4 = NN * DIN / 4;
    hipLaunchKernelGGL(k_cvt16, dim3((n4 + 255) / 256), dim3(256), 0, stream, x, x16, n4);

    // ---------- pre-FFNN ----------
    mg_gelu(stream, x16, preW1t, pre_b1, t16a, NN, HD, DIN);
    mg_both(stream, t16a, preW2t, pre_b2, h32, h16, NN, HD, HD);

    for (int i = 0; i < NL; ++i) {
        const _Float16* uW1 = updW1t + (size_t)i * HD * HD;
        const _Float16* uW2 = updW2t + (size_t)i * HD * H4;
        const _Float16* pW1 = propW1t + (size_t)i * H4 * HD;
        const _Float16* pW2 = propW2t + (size_t)i * HD * HD;
        const _Float16* gW1 = ginW1t + (size_t)i * HD * HD;
        const _Float16* gW2 = ginW2t + (size_t)i * HD * HD;
        const _Float16* fW1 = ffnW1t + (size_t)i * HD * HD;
        const _Float16* fW2 = ffnW2t + (size_t)i * HD * HD;

        // virtual-node path (M = NG = 512) via MFMA GEMMs
        hipLaunchKernelGGL(k_pool16, dim3(NG), dim3(HD), 0, stream, h16, goff, pool16);
        mg_gelu(stream, pool16, uW1, upd_b1 + (size_t)i * HD, u16, NG, HD, HD);
        mg_bias2_16(stream, u16, uW2, upd_b2 + (size_t)i * H4, vn, vb16, NG, H4, HD);
        mg_gelu(stream, vb16, pW1, prop_b1 + (size_t)i * HD, p16, NG, HD, H4);
        mg_f32only(stream, p16, pW2, prop_b2 + (size_t)i * HD, outvn32, NG, HD, HD);

        // GIN: t16a = agg(h16); t16b = gelu(t16a@W1+b); g32 = t16b@W2+b + h32 (+fused BN stats)
        hipLaunchKernelGGL(k_agg16, dim3(NN / 4), dim3(256), 0, stream, h16, eoff, csr, t16a);
        mg_gelu(stream, t16a, gW1, gin_b1 + (size_t)i * HD, t16b, NN, HD, HD);
        mg_res32_stats(stream, t16b, gW2, gin_b2 + (size_t)i * HD, h32, bnstat, g32, NN, HD, HD);

        // BN finalize (re-zeroes stat)
        hipLaunchKernelGGL(k_bn_final, dim3(1), dim3(HD), 0, stream, bnstat,
                           bn_gamma + (size_t)i * HD, bn_beta + (size_t)i * HD, bnscale, bnshift);

        // FFN1 with fused BN+VN A-transform: t16b = gelu((bn(g32)+ovn)@fW1+b)
        mg_gelu_abn(stream, g32, fW1, ffn_b1 + (size_t)i * HD, bnscale, bnshift,
                    outvn32, batch, t16b, NN, HD, HD);
        // FFN2: h32/h16 = t16b@fW2+b + (g32*scale+shift)
        mg_resbn_both(stream, t16b, fW2, ffn_b2 + (size_t)i * HD, g32, bnscale, bnshift,
                      h32, h16, NN, HD, HD);
    }

    // ---------- post ----------
    hipLaunchKernelGGL(k_pool16, dim3(NG), dim3(HD), 0, stream, h16, goff, pool16);
    mg_gelu(stream, pool16, postW1t, post_b1, u16, NG, HD, HD);
    mg_f32only(stream, u16, postW2t, post_b2, out, NG, DOUT, HD);
}

// Round 10
// 1774.666 us; speedup vs baseline: 1.3466x; 1.1070x over previous
//
#include <hip/hip_runtime.h>
#include <hip/hip_bf16.h>
#include <math.h>

#define NN 50000
#define NNP 50048          // padded to multiple of 128
#define NE 800000
#define NG 512
#define DIN 128
#define HD 256
#define DOUT 128
#define NL 5
#define H4 1024

typedef _Float16 f16x8 __attribute__((ext_vector_type(8)));
typedef _Float16 f16x4 __attribute__((ext_vector_type(4)));
typedef float f32x4 __attribute__((ext_vector_type(4)));

__device__ __forceinline__ float gelu_exact(float x) {
    return 0.5f * x * (1.0f + erff(x * 0.70710678118654752f));
}

__device__ __forceinline__ void gl_lds16(const _Float16* g, _Float16* l) {
    __builtin_amdgcn_global_load_lds(
        (const __attribute__((address_space(1))) unsigned int*)g,
        (__attribute__((address_space(3))) unsigned int*)l, 16, 0, 0);
}

// ---------------- graph meta ----------------
__global__ void k_hist(const int* __restrict__ idx, int* __restrict__ cnt, int n) {
    int i = blockIdx.x * blockDim.x + threadIdx.x;
    if (i < n) atomicAdd(&cnt[idx[i]], 1);
}

__global__ void k_scan_small(const int* __restrict__ in, int* __restrict__ out, int n) {
    __shared__ int buf[1024];
    int t = threadIdx.x;
    int v = (t < n) ? in[t] : 0;
    buf[t] = v;
    __syncthreads();
    for (int off = 1; off < 1024; off <<= 1) {
        int x = (t >= off) ? buf[t - off] : 0;
        __syncthreads();
        buf[t] += x;
        __syncthreads();
    }
    if (t < n) out[t] = buf[t] - v;
    if (t == 1023) out[n] = buf[1023];
}

__global__ void k_scan_part(const int* __restrict__ in, int* __restrict__ bsum, int n) {
    __shared__ int buf[256];
    int i = blockIdx.x * 256 + threadIdx.x;
    buf[threadIdx.x] = (i < n) ? in[i] : 0;
    __syncthreads();
    for (int off = 128; off > 0; off >>= 1) {
        if (threadIdx.x < off) buf[threadIdx.x] += buf[threadIdx.x + off];
        __syncthreads();
    }
    if (threadIdx.x == 0) bsum[blockIdx.x] = buf[0];
}

__global__ void k_scan_mid(const int* __restrict__ bsum, int* __restrict__ bexcl, int nb,
                           int* __restrict__ out, int n) {
    __shared__ int buf[1024];
    int t = threadIdx.x;
    int v = (t < nb) ? bsum[t] : 0;
    buf[t] = v;
    __syncthreads();
    for (int off = 1; off < 1024; off <<= 1) {
        int x = (t >= off) ? buf[t - off] : 0;
        __syncthreads();
        buf[t] += x;
        __syncthreads();
    }
    if (t < nb) bexcl[t] = buf[t] - v;
    if (t == 1023) out[n] = buf[1023];
}

__global__ void k_scan_out(const int* __restrict__ in, const int* __restrict__ bexcl,
                           int* __restrict__ out, int n) {
    __shared__ int buf[256];
    int i = blockIdx.x * 256 + threadIdx.x;
    int t = threadIdx.x;
    int v = (i < n) ? in[i] : 0;
    buf[t] = v;
    __syncthreads();
    for (int off = 1; off < 256; off <<= 1) {
        int x = (t >= off) ? buf[t - off] : 0;
        __syncthreads();
        buf[t] += x;
        __syncthreads();
    }
    if (i < n) out[i] = bexcl[blockIdx.x] + buf[t] - v;
}

__global__ void k_fill_csr(const int* __restrict__ src, const int* __restrict__ dst,
                           const int* __restrict__ eoff, int* __restrict__ cursor,
                           int* __restrict__ csr, int n) {
    int e = blockIdx.x * blockDim.x + threadIdx.x;
    if (e < n) {
        int d = dst[e];
        int p = atomicAdd(&cursor[d], 1);
        csr[eoff[d] + p] = src[e];
    }
}

// ---------------- converts ----------------
__global__ void k_cvt16(const float* __restrict__ in, _Float16* __restrict__ out, int n4) {
    int i = blockIdx.x * blockDim.x + threadIdx.x;
    if (i < n4) {
        float4 v = *(const float4*)&in[i * 4];
        f16x4 o = { (_Float16)v.x, (_Float16)v.y, (_Float16)v.z, (_Float16)v.w };
        *(f16x4*)&out[i * 4] = o;
    }
}

// batched transpose + convert: one launch for all weight matrices
#define NWTJOBS 44
struct WtJobs {
    const float* src[NWTJOBS];
    _Float16* dst[NWTJOBS];
    short K32[NWTJOBS];
    short N32[NWTJOBS];
    short pre[NWTJOBS + 1];
};
__global__ void k_wtb(WtJobs j) {
    int bid = blockIdx.x;
    int lo = 0;
    while (j.pre[lo + 1] <= bid) ++lo;
    int tl = bid - j.pre[lo];
    int nx = j.N32[lo];
    int n0 = (tl % nx) * 32, k0 = (tl / nx) * 32;
    int K = j.K32[lo] * 32, N = nx * 32;
    const float* W = j.src[lo];
    _Float16* Wt = j.dst[lo];
    __shared__ float tile[32][33];
    for (int i = threadIdx.y; i < 32; i += 8)
        tile[i][threadIdx.x] = W[(size_t)(k0 + i) * N + n0 + threadIdx.x];
    __syncthreads();
    for (int i = threadIdx.y; i < 32; i += 8)
        Wt[(size_t)(n0 + i) * K + k0 + threadIdx.x] = (_Float16)tile[threadIdx.x][i];
}

// ---------------- pooling / aggregation ----------------
__global__ void k_pool16(const _Float16* __restrict__ h16, const int* __restrict__ goff,
                         _Float16* __restrict__ pool) {
    int g = blockIdx.x;
    int c = threadIdx.x;
    int s = goff[g], e = goff[g + 1];
    float acc = 0.f;
    for (int r = s; r < e; ++r) acc += (float)h16[(size_t)r * HD + c];
    int cnt = e - s;
    pool[g * HD + c] = (_Float16)(acc / (float)(cnt > 0 ? cnt : 1));
}

// one wave per node; WAVE-UNIFORM loop bounds; 8 edges/iter
__global__ __launch_bounds__(256) void k_agg16(const _Float16* __restrict__ h16,
                                               const int* __restrict__ eoff,
                                               const int* __restrict__ csr,
                                               _Float16* __restrict__ out) {
    int node = blockIdx.x * 4 + (threadIdx.x >> 6);
    int lane = threadIdx.x & 63;
    int half = lane >> 5, l = lane & 31;
    f16x8 mine = *(const f16x8*)&h16[(size_t)node * HD + l * 8];
    float acc[8];
#pragma unroll
    for (int q = 0; q < 8; ++q) acc[q] = half ? 0.f : (float)mine[q];
    int s = eoff[node], e = eoff[node + 1];
    for (int base = s; base < e; base += 64) {
        int myi = base + lane;
        int vidx = (myi < e) ? csr[myi] : 0;
        int cnt = min(64, e - base);
        int jj = 0;
        for (; jj + 7 < cnt; jj += 8) {
            int s0 = __shfl(vidx, jj + half);
            int s1 = __shfl(vidx, jj + 2 + half);
            int s2 = __shfl(vidx, jj + 4 + half);
            int s3 = __shfl(vidx, jj + 6 + half);
            f16x8 v0 = *(const f16x8*)&h16[(size_t)s0 * HD + l * 8];
            f16x8 v1 = *(const f16x8*)&h16[(size_t)s1 * HD + l * 8];
            f16x8 v2 = *(const f16x8*)&h16[(size_t)s2 * HD + l * 8];
            f16x8 v3 = *(const f16x8*)&h16[(size_t)s3 * HD + l * 8];
#pragma unroll
            for (int q = 0; q < 8; ++q)
                acc[q] += ((float)v0[q] + (float)v1[q]) + ((float)v2[q] + (float)v3[q]);
        }
        for (; jj + 3 < cnt; jj += 4) {
            int s0 = __shfl(vidx, jj + half);
            int s1 = __shfl(vidx, jj + 2 + half);
            f16x8 v0 = *(const f16x8*)&h16[(size_t)s0 * HD + l * 8];
            f16x8 v1 = *(const f16x8*)&h16[(size_t)s1 * HD + l * 8];
#pragma unroll
            for (int q = 0; q < 8; ++q) acc[q] += (float)v0[q] + (float)v1[q];
        }
        for (; jj < cnt; jj += 2) {
            int i0 = jj + half;
            int s0 = __shfl(vidx, i0);
            if (i0 < cnt) {
                f16x8 v0 = *(const f16x8*)&h16[(size_t)s0 * HD + l * 8];
#pragma unroll
                for (int q = 0; q < 8; ++q) acc[q] += (float)v0[q];
            }
        }
    }
#pragma unroll
    for (int q = 0; q < 8; ++q) acc[q] += __shfl_xor(acc[q], 32);
    if (!half) {
        f16x8 o;
#pragma unroll
        for (int q = 0; q < 8; ++q) o[q] = (_Float16)acc[q];
        *(f16x8*)&out[(size_t)node * HD + l * 8] = o;
    }
}

// ---------------- batch norm finalize (also re-zeroes stat for next layer) ----
__global__ void k_bn_final(float* __restrict__ stat,
                           const float* __restrict__ gamma, const float* __restrict__ beta,
                           float* __restrict__ scale, float* __restrict__ shift) {
    int c = threadIdx.x;
    float mu = stat[c] * (1.0f / NN);
    float var = stat[HD + c] * (1.0f / NN) - mu * mu;
    float rs = rsqrtf(var + 1e-5f);
    float sc = rs * gamma[c];
    scale[c] = sc;
    shift[c] = beta[c] - mu * sc;
    stat[c] = 0.f;
    stat[HD + c] = 0.f;
}

__device__ __forceinline__ void bnpack(float4 g0, float4 g1, float4 s0, float4 s1,
                                       float4 h0, float4 h1, float4 o0, float4 o1, f16x8& r) {
    r[0] = (_Float16)(g0.x * s0.x + h0.x + o0.x);
    r[1] = (_Float16)(g0.y * s0.y + h0.y + o0.y);
    r[2] = (_Float16)(g0.z * s0.z + h0.z + o0.z);
    r[3] = (_Float16)(g0.w * s0.w + h0.w + o0.w);
    r[4] = (_Float16)(g1.x * s1.x + h1.x + o1.x);
    r[5] = (_Float16)(g1.y * s1.y + h1.y + o1.y);
    r[6] = (_Float16)(g1.z * s1.z + h1.z + o1.z);
    r[7] = (_Float16)(g1.w * s1.w + h1.w + o1.w);
}

// ======== fused back-to-back FFNN: C2 = gelu(A@W1+b1)@W2+b2 [+res] ========
// 64 rows x full N=256; 512 threads (8 waves x 32 cols); K2 = 256 fixed.
// ABN1: A from fp32 g32 with bn+vn transform.  Stage-2 epilogue flags as before.
template <bool ABN1, bool RES2, bool RESBN2, bool STATS2, bool O32, bool O16>
__global__ __launch_bounds__(512) void k_b2b(const _Float16* __restrict__ A16,
                                             const float* __restrict__ A32,
                                             const _Float16* __restrict__ W1t,
                                             const float* __restrict__ b1,
                                             const _Float16* __restrict__ W2t,
                                             const float* __restrict__ b2,
                                             const float* __restrict__ R32,
                                             const float* __restrict__ bnsc,
                                             const float* __restrict__ bnsh,
                                             const float* __restrict__ ovn,
                                             const int* __restrict__ batchv,
                                             float* __restrict__ stat,
                                             float* __restrict__ C32,
                                             _Float16* __restrict__ C16,
                                             int M, int K1) {
    __shared__ _Float16 As[2][4][64][8];    // 8 KB
    __shared__ _Float16 Bs[2][4][256][8];   // 32 KB
    __shared__ _Float16 C1L[32][64][8];     // 32 KB
    const int t = threadIdx.x;
    const int w = t >> 6, lane = t & 63;
    const int m0 = blockIdx.x * 64;
    const int kb = lane >> 4, fr = lane & 15, rr = lane >> 4;

    // B staging (256 rows x one 32-k window): 1024 16B-slots, 2 per thread
    auto stageB = [&](int buf, int k0, const _Float16* Wt, int KB) {
        int s0 = t, s1 = t + 512;
        gl_lds16(Wt + (size_t)(s0 & 255) * KB + k0 + (s0 >> 8) * 8, &Bs[buf][s0 >> 8][s0 & 255][0]);
        gl_lds16(Wt + (size_t)(s1 & 255) * KB + k0 + (s1 >> 8) * 8, &Bs[buf][s1 >> 8][s1 & 255][0]);
    };
    // A staging
    int b0 = 0;
    if constexpr (ABN1) {
        if (t < 256) b0 = batchv[min(m0 + (t & 63), M - 1)];
    }
    auto stageA = [&](int buf, int k0) {
        if constexpr (ABN1) {
            if (t < 256) {
                int ar = t & 63, akb = t >> 6;
                const int c0 = k0 + akb * 8;
                float4 s0 = *(const float4*)&bnsc[c0];
                float4 s1 = *(const float4*)&bnsc[c0 + 4];
                float4 h0 = *(const float4*)&bnsh[c0];
                float4 h1 = *(const float4*)&bnsh[c0 + 4];
                const float* ga = A32 + (size_t)(m0 + ar) * HD + c0;
                float4 ga0 = *(const float4*)ga;
                float4 ga1 = *(const float4*)(ga + 4);
                float4 oa0 = *(const float4*)&ovn[(size_t)b0 * HD + c0];
                float4 oa1 = *(const float4*)&ovn[(size_t)b0 * HD + c0 + 4];
                f16x8 r0;
                bnpack(ga0, ga1, s0, s1, h0, h1, oa0, oa1, r0);
                *(f16x8*)&As[buf][akb][ar][0] = r0;
            }
        } else {
            if (w < 4)
                gl_lds16(A16 + (size_t)(m0 + lane) * K1 + k0 + w * 8, &As[buf][w][lane][0]);
        }
    };

    // ---- stage 1 ----
    f32x4 acc1[4][2];
#pragma unroll
    for (int mi = 0; mi < 4; ++mi)
#pragma unroll
        for (int ni = 0; ni < 2; ++ni) acc1[mi][ni] = (f32x4){0.f, 0.f, 0.f, 0.f};

    const int nt1 = K1 >> 5;
    stageA(0, 0);
    stageB(0, 0, W1t, K1);
    __syncthreads();
    for (int tt = 0; tt < nt1; ++tt) {
        const int cur = tt & 1;
        if (tt + 1 < nt1) {
            stageA(cur ^ 1, (tt + 1) << 5);
            stageB(cur ^ 1, (tt + 1) << 5, W1t, K1);
        }
        f16x8 af[4], bf[2];
#pragma unroll
        for (int mi = 0; mi < 4; ++mi)
            af[mi] = *(const f16x8*)&As[cur][kb][mi * 16 + fr][0];
#pragma unroll
        for (int ni = 0; ni < 2; ++ni)
            bf[ni] = *(const f16x8*)&Bs[cur][kb][w * 32 + ni * 16 + fr][0];
#pragma unroll
        for (int mi = 0; mi < 4; ++mi)
#pragma unroll
            for (int ni = 0; ni < 2; ++ni)
                acc1[mi][ni] = __builtin_amdgcn_mfma_f32_16x16x32_f16(af[mi], bf[ni], acc1[mi][ni], 0, 0, 0);
        __syncthreads();
    }

    // issue first W2 tile while writing C1 to LDS
    stageB(0, 0, W2t, HD);
#pragma unroll
    for (int mi = 0; mi < 4; ++mi) {
#pragma unroll
        for (int reg = 0; reg < 4; ++reg) {
            int ml = mi * 16 + rr * 4 + reg;
#pragma unroll
            for (int ni = 0; ni < 2; ++ni) {
                int n = w * 32 + ni * 16 + fr;
                float v = gelu_exact(acc1[mi][ni][reg] + b1[n]);
                C1L[n >> 3][ml][n & 7] = (_Float16)v;
            }
        }
    }
    __syncthreads();

    // ---- stage 2 (K2 = 256) ----
    f32x4 acc2[4][2];
#pragma unroll
    for (int mi = 0; mi < 4; ++mi)
#pragma unroll
        for (int ni = 0; ni < 2; ++ni) acc2[mi][ni] = (f32x4){0.f, 0.f, 0.f, 0.f};

    for (int tt = 0; tt < 8; ++tt) {
        const int cur = tt & 1;
        if (tt + 1 < 8) stageB(cur ^ 1, (tt + 1) << 5, W2t, HD);
        f16x8 af[4], bf[2];
#pragma unroll
        for (int mi = 0; mi < 4; ++mi)
            af[mi] = *(const f16x8*)&C1L[tt * 4 + kb][mi * 16 + fr][0];
#pragma unroll
        for (int ni = 0; ni < 2; ++ni)
            bf[ni] = *(const f16x8*)&Bs[cur][kb][w * 32 + ni * 16 + fr][0];
#pragma unroll
        for (int mi = 0; mi < 4; ++mi)
#pragma unroll
            for (int ni = 0; ni < 2; ++ni)
                acc2[mi][ni] = __builtin_amdgcn_mfma_f32_16x16x32_f16(af[mi], bf[ni], acc2[mi][ni], 0, 0, 0);
        __syncthreads();
    }

    // ---- epilogue 2 ----
    float cs[2] = {0.f, 0.f}, cq[2] = {0.f, 0.f};
#pragma unroll
    for (int mi = 0; mi < 4; ++mi) {
#pragma unroll
        for (int reg = 0; reg < 4; ++reg) {
            int m = m0 + mi * 16 + rr * 4 + reg;
            if (m < M) {
#pragma unroll
                for (int ni = 0; ni < 2; ++ni) {
                    int n = w * 32 + ni * 16 + fr;
                    float v = acc2[mi][ni][reg] + b2[n];
                    if (RES2) v += R32[(size_t)m * HD + n];
                    if (RESBN2) v += R32[(size_t)m * HD + n] * bnsc[n] + bnsh[n];
                    if (O32) C32[(size_t)m * HD + n] = v;
                    if (O16) C16[(size_t)m * HD + n] = (_Float16)v;
                    if (STATS2) { cs[ni] += v; cq[ni] += v * v; }
                }
            }
        }
    }
    if constexpr (STATS2) {
#pragma unroll
        for (int ni = 0; ni < 2; ++ni) {
            cs[ni] += __shfl_xor(cs[ni], 16); cs[ni] += __shfl_xor(cs[ni], 32);
            cq[ni] += __shfl_xor(cq[ni], 16); cq[ni] += __shfl_xor(cq[ni], 32);
        }
        if (lane < 16) {
#pragma unroll
            for (int ni = 0; ni < 2; ++ni) {
                int n = w * 32 + ni * 16 + lane;
                atomicAdd(&stat[n], cs[ni]);
                atomicAdd(&stat[HD + n], cq[ni]);
            }
        }
    }
}

// ---------------- MFMA fp16 GEMM (64x128 tile) — VN/post path ----------------
template <bool GELU, bool BIAS2, bool O32, bool O16>
__global__ __launch_bounds__(256) void k_mgemm(const _Float16* __restrict__ A,
                                               const _Float16* __restrict__ Wt,
                                               const float* __restrict__ bias,
                                               const float* __restrict__ bias2,
                                               float* __restrict__ C32,
                                               _Float16* __restrict__ C16,
                                               int M, int N, int K) {
    __shared__ _Float16 As[2][4][64][8];
    __shared__ _Float16 Bs[2][4][128][8];
    const int t = threadIdx.x;
    const int w = t >> 6, lane = t & 63;
    const int m0 = blockIdx.y * 64, n0 = blockIdx.x * 128;
    const int kb = lane >> 4, fr = lane & 15;

    f32x4 acc[4][2];
#pragma unroll
    for (int mi = 0; mi < 4; ++mi)
#pragma unroll
        for (int ni = 0; ni < 2; ++ni) acc[mi][ni] = (f32x4){0.f, 0.f, 0.f, 0.f};

    const _Float16* gA0 = A + (size_t)(m0 + lane) * K + w * 8;
    const _Float16* gB0 = Wt + (size_t)(n0 + lane) * K + w * 8;
    const _Float16* gB1 = Wt + (size_t)(n0 + 64 + lane) * K + w * 8;

    auto stage = [&](int buf, int k0) {
        gl_lds16(gB0 + k0, &Bs[buf][w][0][0]);
        gl_lds16(gB1 + k0, &Bs[buf][w][64][0]);
        gl_lds16(gA0 + k0, &As[buf][w][0][0]);
    };

    const int nt = K >> 5;
    stage(0, 0);
    __syncthreads();
    for (int tt = 0; tt < nt; ++tt) {
        const int cur = tt & 1;
        if (tt + 1 < nt) stage(cur ^ 1, (tt + 1) << 5);
        f16x8 af[4], bf[2];
#pragma unroll
        for (int mi = 0; mi < 4; ++mi)
            af[mi] = *(const f16x8*)&As[cur][kb][mi * 16 + fr][0];
#pragma unroll
        for (int ni = 0; ni < 2; ++ni)
            bf[ni] = *(const f16x8*)&Bs[cur][kb][w * 32 + ni * 16 + fr][0];
#pragma unroll
        for (int mi = 0; mi < 4; ++mi)
#pragma unroll
            for (int ni = 0; ni < 2; ++ni)
                acc[mi][ni] = __builtin_amdgcn_mfma_f32_16x16x32_f16(af[mi], bf[ni], acc[mi][ni], 0, 0, 0);
        __syncthreads();
    }

    const int rr = lane >> 4;
#pragma unroll
    for (int mi = 0; mi < 4; ++mi) {
#pragma unroll
        for (int reg = 0; reg < 4; ++reg) {
            int m = m0 + mi * 16 + rr * 4 + reg;
            if (m < M) {
#pragma unroll
                for (int ni = 0; ni < 2; ++ni) {
                    int n = n0 + w * 32 + ni * 16 + fr;
                    float v = acc[mi][ni][reg] + bias[n];
                    if (BIAS2) v += bias2[n];
                    if (GELU) v = gelu_exact(v);
                    if (O32) C32[(size_t)m * N + n] = v;
                    if (O16) C16[(size_t)m * N + n] = (_Float16)v;
                }
            }
        }
    }
}

static inline void mg_gelu(hipStream_t st, const _Float16* A, const _Float16* Wt,
                           const float* bias, _Float16* C16, int M, int N, int K) {
    dim3 g(N / 128, (M + 63) / 64), b(256);
    k_mgemm<true, false, false, true><<<g, b, 0, st>>>(A, Wt, bias, nullptr, nullptr, C16, M, N, K);
}
static inline void mg_bias2_16(hipStream_t st, const _Float16* A, const _Float16* Wt,
                               const float* bias, const float* bias2, _Float16* C16,
                               int M, int N, int K) {
    dim3 g(N / 128, (M + 63) / 64), b(256);
    k_mgemm<false, true, false, true><<<g, b, 0, st>>>(A, Wt, bias, bias2, nullptr, C16, M, N, K);
}
static inline void mg_f32only(hipStream_t st, const _Float16* A, const _Float16* Wt,
                              const float* bias, float* C32, int M, int N, int K) {
    dim3 g(N / 128, (M + 63) / 64), b(256);
    k_mgemm<false, false, true, false><<<g, b, 0, st>>>(A, Wt, bias, nullptr, C32, nullptr, M, N, K);
}

extern "C" void kernel_launch(void* const* d_in, const int* in_sizes, int n_in,
                              void* d_out, int out_size, void* d_ws, size_t ws_size,
                              hipStream_t stream) {
    const float* x       = (const float*)d_in[0];
    const int*   ei      = (const int*)d_in[1];
    const int*   batch   = (const int*)d_in[2];
    const float* pre_W1  = (const float*)d_in[3];
    const float* pre_b1  = (const float*)d_in[4];
    const float* pre_W2  = (const float*)d_in[5];
    const float* pre_b2  = (const float*)d_in[6];
    const float* gin_W1  = (const float*)d_in[7];
    const float* gin_b1  = (const float*)d_in[8];
    const float* gin_W2  = (const float*)d_in[9];
    const float* gin_b2  = (const float*)d_in[10];
    const float* ffn_W1  = (const float*)d_in[11];
    const float* ffn_b1  = (const float*)d_in[12];
    const float* ffn_W2  = (const float*)d_in[13];
    const float* ffn_b2  = (const float*)d_in[14];
    const float* upd_W1  = (const float*)d_in[15];
    const float* upd_b1  = (const float*)d_in[16];
    const float* upd_W2  = (const float*)d_in[17];
    const float* upd_b2  = (const float*)d_in[18];
    const float* prop_W1 = (const float*)d_in[19];
    const float* prop_b1 = (const float*)d_in[20];
    const float* prop_W2 = (const float*)d_in[21];
    const float* prop_b2 = (const float*)d_in[22];
    const float* bn_gamma= (const float*)d_in[23];
    const float* bn_beta = (const float*)d_in[24];
    const float* vn      = (const float*)d_in[25];
    const float* post_W1 = (const float*)d_in[26];
    const float* post_b1 = (const float*)d_in[27];
    const float* post_W2 = (const float*)d_in[28];
    const float* post_b2 = (const float*)d_in[29];
    float* out = (float*)d_out;

    const int* e_src = ei;
    const int* e_dst = ei + NE;

    // ---------- workspace layout ----------
    char* p = (char*)d_ws;
    auto alloc = [&](size_t bytes) -> char* {
        char* r = p;
        p += (bytes + 255) & ~(size_t)255;
        return r;
    };
    float*    h32    = (float*)alloc((size_t)NNP * HD * 4);
    float*    g32    = (float*)alloc((size_t)NNP * HD * 4);
    _Float16* h16    = (_Float16*)alloc((size_t)NNP * HD * 2);
    _Float16* t16a   = (_Float16*)alloc((size_t)NNP * HD * 2);  // agg out; aliases x16 pre-launch
    _Float16* pool16 = (_Float16*)alloc((size_t)NG * HD * 2);
    _Float16* u16    = (_Float16*)alloc((size_t)NG * HD * 2);
    _Float16* vb16   = (_Float16*)alloc((size_t)NG * H4 * 2);
    _Float16* p16    = (_Float16*)alloc((size_t)NG * HD * 2);
    float*    outvn32= (float*)alloc((size_t)NG * HD * 4);
    float*    bnstat = (float*)alloc(2 * HD * 4);
    float*    bnscale= (float*)alloc(HD * 4);
    float*    bnshift= (float*)alloc(HD * 4);
    _Float16* preW1t = (_Float16*)alloc((size_t)HD * DIN * 2);
    _Float16* preW2t = (_Float16*)alloc((size_t)HD * HD * 2);
    _Float16* ginW1t = (_Float16*)alloc((size_t)NL * HD * HD * 2);
    _Float16* ginW2t = (_Float16*)alloc((size_t)NL * HD * HD * 2);
    _Float16* ffnW1t = (_Float16*)alloc((size_t)NL * HD * HD * 2);
    _Float16* ffnW2t = (_Float16*)alloc((size_t)NL * HD * HD * 2);
    _Float16* updW1t = (_Float16*)alloc((size_t)NL * HD * HD * 2);
    _Float16* updW2t = (_Float16*)alloc((size_t)NL * HD * H4 * 2);
    _Float16* propW1t= (_Float16*)alloc((size_t)NL * H4 * HD * 2);
    _Float16* propW2t= (_Float16*)alloc((size_t)NL * HD * HD * 2);
    _Float16* postW1t= (_Float16*)alloc((size_t)HD * HD * 2);
    _Float16* postW2t= (_Float16*)alloc((size_t)DOUT * HD * 2);
    int* gcount = (int*)alloc(NG * 4);
    int* goff   = (int*)alloc((NG + 1) * 4);
    int* deg    = (int*)alloc(NN * 4);
    int* eoff   = (int*)alloc((NN + 1) * 4);
    int* cursor = (int*)alloc(NN * 4);
    int* csr    = (int*)alloc((size_t)NE * 4);
    int* bsum   = (int*)alloc(1024 * 4);
    int* bexcl  = (int*)alloc(1024 * 4);
    _Float16* x16 = t16a;   // alias: consumed by pre-pair before t16a is first written

    // ---------- zero counters + bnstat ----------
    {
        size_t span = (size_t)((char*)(cursor + NN) - (char*)gcount);
        hipMemsetAsync(gcount, 0, span, stream);
        hipMemsetAsync(bnstat, 0, 2 * HD * 4, stream);
    }
    hipLaunchKernelGGL(k_hist, dim3((NN + 255) / 256), dim3(256), 0, stream, batch, gcount, NN);
    hipLaunchKernelGGL(k_hist, dim3((NE + 255) / 256), dim3(256), 0, stream, e_dst, deg, NE);
    hipLaunchKernelGGL(k_scan_small, dim3(1), dim3(1024), 0, stream, gcount, goff, NG);
    {
        int nbN = (NN + 255) / 256;
        hipLaunchKernelGGL(k_scan_part, dim3(nbN), dim3(256), 0, stream, deg, bsum, NN);
        hipLaunchKernelGGL(k_scan_mid, dim3(1), dim3(1024), 0, stream, bsum, bexcl, nbN, eoff, NN);
        hipLaunchKernelGGL(k_scan_out, dim3(nbN), dim3(256), 0, stream, deg, bexcl, eoff, NN);
    }
    hipLaunchKernelGGL(k_fill_csr, dim3((NE + 255) / 256), dim3(256), 0, stream, e_src, e_dst, eoff, cursor, csr, NE);

    // ---------- batched weight transpose (one launch) ----------
    {
        WtJobs j;
        int idx = 0, tiles = 0;
        auto add = [&](const float* s, _Float16* d, int K, int N) {
            j.src[idx] = s; j.dst[idx] = d;
            j.K32[idx] = (short)(K / 32); j.N32[idx] = (short)(N / 32);
            j.pre[idx] = (short)tiles;
            tiles += (K / 32) * (N / 32);
            ++idx;
        };
        add(pre_W1, preW1t, DIN, HD);
        add(pre_W2, preW2t, HD, HD);
        add(post_W1, postW1t, HD, HD);
        add(post_W2, postW2t, HD, DOUT);
        for (int i = 0; i < NL; ++i) {
            add(gin_W1 + (size_t)i * HD * HD, ginW1t + (size_t)i * HD * HD, HD, HD);
            add(gin_W2 + (size_t)i * HD * HD, ginW2t + (size_t)i * HD * HD, HD, HD);
            add(ffn_W1 + (size_t)i * HD * HD, ffnW1t + (size_t)i * HD * HD, HD, HD);
            add(ffn_W2 + (size_t)i * HD * HD, ffnW2t + (size_t)i * HD * HD, HD, HD);
            add(upd_W1 + (size_t)i * HD * HD, updW1t + (size_t)i * HD * HD, HD, HD);
            add(upd_W2 + (size_t)i * HD * H4, updW2t + (size_t)i * HD * H4, HD, H4);
            add(prop_W1 + (size_t)i * H4 * HD, propW1t + (size_t)i * H4 * HD, H4, HD);
            add(prop_W2 + (size_t)i * HD * HD, propW2t + (size_t)i * HD * HD, HD, HD);
        }
        j.pre[idx] = (short)tiles;
        hipLaunchKernelGGL(k_wtb, dim3(tiles), dim3(32, 8), 0, stream, j);
    }

    // x -> fp16
    int n4 = NN * DIN / 4;
    hipLaunchKernelGGL(k_cvt16, dim3((n4 + 255) / 256), dim3(256), 0, stream, x, x16, n4);

    const int nb2b = NNP / 64;

    // ---------- pre-FFNN (fused pair): h32/h16 = gelu(x@W1+b1)@W2+b2 ----------
    hipLaunchKernelGGL((k_b2b<false, false, false, false, true, true>), dim3(nb2b), dim3(512), 0, stream,
                       x16, nullptr, preW1t, pre_b1, preW2t, pre_b2,
                       nullptr, nullptr, nullptr, nullptr, nullptr, nullptr,
                       h32, h16, NN, DIN);

    for (int i = 0; i < NL; ++i) {
        const _Float16* uW1 = updW1t + (size_t)i * HD * HD;
        const _Float16* uW2 = updW2t + (size_t)i * HD * H4;
        const _Float16* pW1 = propW1t + (size_t)i * H4 * HD;
        const _Float16* pW2 = propW2t + (size_t)i * HD * HD;

        // virtual-node path (M = NG = 512)
        hipLaunchKernelGGL(k_pool16, dim3(NG), dim3(HD), 0, stream, h16, goff, pool16);
        mg_gelu(stream, pool16, uW1, upd_b1 + (size_t)i * HD, u16, NG, HD, HD);
        mg_bias2_16(stream, u16, uW2, upd_b2 + (size_t)i * H4, vn, vb16, NG, H4, HD);
        mg_gelu(stream, vb16, pW1, prop_b1 + (size_t)i * HD, p16, NG, HD, H4);
        mg_f32only(stream, p16, pW2, prop_b2 + (size_t)i * HD, outvn32, NG, HD, HD);

        // GIN: t16a = agg(h16); g32 = gelu(t16a@gW1+b1)@gW2+b2 + h32 (+BN stats)
        hipLaunchKernelGGL(k_agg16, dim3(NN / 4), dim3(256), 0, stream, h16, eoff, csr, t16a);
        hipLaunchKernelGGL((k_b2b<false, true, false, true, true, false>), dim3(nb2b), dim3(512), 0, stream,
                           t16a, nullptr,
                           ginW1t + (size_t)i * HD * HD, gin_b1 + (size_t)i * HD,
                           ginW2t + (size_t)i * HD * HD, gin_b2 + (size_t)i * HD,
                           h32, nullptr, nullptr, nullptr, nullptr, bnstat,
                           g32, nullptr, NN, HD);

        // BN finalize (re-zeroes stat)
        hipLaunchKernelGGL(k_bn_final, dim3(1), dim3(HD), 0, stream, bnstat,
                           bn_gamma + (size_t)i * HD, bn_beta + (size_t)i * HD, bnscale, bnshift);

        // FFN fused pair: h32/h16 = gelu((bn(g32)+ovn)@fW1+b1)@fW2+b2 + bn(g32)
        hipLaunchKernelGGL((k_b2b<true, false, true, false, true, true>), dim3(nb2b), dim3(512), 0, stream,
                           nullptr, g32,
                           ffnW1t + (size_t)i * HD * HD, ffn_b1 + (size_t)i * HD,
                           ffnW2t + (size_t)i * HD * HD, ffn_b2 + (size_t)i * HD,
                           g32, bnscale, bnshift, outvn32, batch, nullptr,
                           h32, h16, NN, HD);
    }

    // ---------- post ----------
    hipLaunchKernelGGL(k_pool16, dim3(NG), dim3(HD), 0, stream, h16, goff, pool16);
    mg_gelu(stream, pool16, postW1t, post_b1, u16, NG, HD, HD);
    mg_f32only(stream, u16, postW2t, post_b2, out, NG, DOUT, HD);
}